// Round 1
// baseline (740.751 us; speedup 1.0000x reference)
//
#include <hip/hip_runtime.h>

// GCN forward: 4 x (X@W -> gather-normalize-scatter -> +b, ReLU) -> mean pool -> linear
// N=50000 nodes, E=800000 edges, D=64, L=4, G=64.
// Plan: build CSR by dst once per call (hist -> scan -> scatter), then each layer's
// aggregation is a pure gather (wave per node, lane per feature), no float atomics.

#define D 64
#define SCAN_THREADS 1024
#define POOL_CHUNK 128

// ---- CSR build ----------------------------------------------------------

__global__ void hist_kernel(const int* __restrict__ dst, int* __restrict__ cnt, int e) {
    int i = blockIdx.x * blockDim.x + threadIdx.x;
    if (i < e) atomicAdd(&cnt[dst[i]], 1);
}

__global__ __launch_bounds__(SCAN_THREADS) void scan_kernel(
        const int* __restrict__ cnt, int* __restrict__ row_start,
        int* __restrict__ cursor, float* __restrict__ dinv, int n) {
    __shared__ int tsum[SCAN_THREADS];
    int t = threadIdx.x;
    int per = (n + SCAN_THREADS - 1) / SCAN_THREADS;
    int begin = t * per;
    int end = min(begin + per, n);
    int s = 0;
    for (int i = begin; i < end; ++i) s += cnt[i];
    tsum[t] = s;
    __syncthreads();
    // Hillis-Steele inclusive scan over per-thread sums
    for (int off = 1; off < SCAN_THREADS; off <<= 1) {
        int v = (t >= off) ? tsum[t - off] : 0;
        __syncthreads();
        tsum[t] += v;
        __syncthreads();
    }
    int run = tsum[t] - s;  // exclusive prefix for this thread's range
    for (int i = begin; i < end; ++i) {
        int c = cnt[i];
        row_start[i] = run;
        cursor[i]    = run;
        // deg includes self-loop -> always >= 1. Precise rsqrt (not v_rsq approx).
        dinv[i] = 1.0f / sqrtf((float)(c + 1));
        run += c;
    }
    if (t == SCAN_THREADS - 1) row_start[n] = run;  // == E
}

__global__ void scatter_kernel(const int* __restrict__ src, const int* __restrict__ dst,
                               int* __restrict__ cursor, int* __restrict__ csr_src, int e) {
    int i = blockIdx.x * blockDim.x + threadIdx.x;
    if (i < e) {
        int pos = atomicAdd(&cursor[dst[i]], 1);
        csr_src[pos] = src[i];
    }
}

// ---- per-layer: H = X @ W  (32 rows per 256-thread block) ---------------

__global__ __launch_bounds__(256) void matmul_kernel(
        const float* __restrict__ X, const float* __restrict__ W,
        float* __restrict__ H, int n) {
    __shared__ __align__(16) float Ws[D][D];   // 16 KB
    __shared__ __align__(16) float Xs[32][D];  // 8 KB
    int t = threadIdx.x;
    // load W (64x64) as float4
    const float4* W4 = (const float4*)W;
    float4* Ws4 = (float4*)&Ws[0][0];
    #pragma unroll
    for (int i = t; i < D * D / 4; i += 256) Ws4[i] = W4[i];
    // load X tile (32 rows) as float4
    int rowBase = blockIdx.x * 32;
    const float4* X4 = (const float4*)X;
    float4* Xs4 = (float4*)&Xs[0][0];
    #pragma unroll
    for (int i = t; i < 32 * D / 4; i += 256) {
        int rl = i >> 4;            // local row (16 float4 per row)
        int c4 = i & 15;
        int r = rowBase + rl;
        float4 v = make_float4(0.f, 0.f, 0.f, 0.f);
        if (r < n) v = X4[(size_t)r * (D / 4) + c4];
        Xs4[i] = v;
    }
    __syncthreads();
    int wave = t >> 6, lane = t & 63;
    int r0 = wave * 8;  // each wave computes 8 rows, lane = output col
    float acc[8] = {0.f, 0.f, 0.f, 0.f, 0.f, 0.f, 0.f, 0.f};
    #pragma unroll
    for (int k = 0; k < D; ++k) {
        float w = Ws[k][lane];         // lane-stride-1: 2-way (free)
        #pragma unroll
        for (int j = 0; j < 8; ++j)
            acc[j] += Xs[r0 + j][k] * w;  // broadcast (free)
    }
    #pragma unroll
    for (int j = 0; j < 8; ++j) {
        int r = rowBase + r0 + j;
        if (r < n) H[(size_t)r * D + lane] = acc[j];
    }
}

// ---- per-layer: aggregate + bias + ReLU (wave per node, lane per feat) --

__global__ __launch_bounds__(256) void agg_kernel(
        const float* __restrict__ H, const int* __restrict__ csr_src,
        const int* __restrict__ row_start, const float* __restrict__ dinv,
        const float* __restrict__ bias, float* __restrict__ out, int n) {
    int wave = threadIdx.x >> 6, lane = threadIdx.x & 63;
    int v = blockIdx.x * 4 + wave;
    if (v >= n) return;
    float dv = dinv[v];
    // self-loop contribution: dv * H[v]  (outer dv applied at the end)
    float acc = dv * H[(size_t)v * D + lane];
    int s = row_start[v];
    int e = row_start[v + 1];
    for (int i = s; i < e; ++i) {
        int u = csr_src[i];                       // wave-uniform
        acc += dinv[u] * H[(size_t)u * D + lane]; // 256B coalesced gather
    }
    out[(size_t)v * D + lane] = fmaxf(dv * acc + bias[lane], 0.f);
}

// ---- mean pool (batch sorted: accumulate in regs, flush on group change) -

__global__ __launch_bounds__(256) void pool_kernel(
        const float* __restrict__ X, const int* __restrict__ batch,
        float* __restrict__ sums, int* __restrict__ counts, int n) {
    int wave = threadIdx.x >> 6, lane = threadIdx.x & 63;
    int w = blockIdx.x * 4 + wave;
    int begin = w * POOL_CHUNK;
    if (begin >= n) return;
    int end = min(begin + POOL_CHUNK, n);
    int cur = batch[begin];
    float acc = 0.f;
    int cnt = 0;
    for (int v = begin; v < end; ++v) {
        int g = batch[v];  // wave-uniform broadcast
        if (g != cur) {
            atomicAdd(&sums[cur * D + lane], acc);
            if (lane == 0) atomicAdd(&counts[cur], cnt);
            acc = 0.f; cnt = 0; cur = g;
        }
        acc += X[(size_t)v * D + lane];
        ++cnt;
    }
    atomicAdd(&sums[cur * D + lane], acc);
    if (lane == 0) atomicAdd(&counts[cur], cnt);
}

__global__ void final_kernel(const float* __restrict__ sums, const int* __restrict__ counts,
                             const float* __restrict__ linW, const float* __restrict__ linb,
                             float* __restrict__ out) {
    int g = blockIdx.x;
    int lane = threadIdx.x;  // blockDim = 64
    float p = sums[g * D + lane] * linW[lane];
    #pragma unroll
    for (int off = 32; off > 0; off >>= 1) p += __shfl_down(p, off, 64);
    if (lane == 0) out[g] = p / fmaxf((float)counts[g], 1.f) + linb[0];
}

// ---- orchestration -------------------------------------------------------

extern "C" void kernel_launch(void* const* d_in, const int* in_sizes, int n_in,
                              void* d_out, int out_size, void* d_ws, size_t ws_size,
                              hipStream_t stream) {
    const float* x      = (const float*)d_in[0];  // [N,64]
    const float* conv_W = (const float*)d_in[1];  // [4,64,64]
    const float* conv_b = (const float*)d_in[2];  // [4,64]
    const float* lin_W  = (const float*)d_in[3];  // [64,1]
    const float* lin_b  = (const float*)d_in[4];  // [1]
    const int*   edge   = (const int*)d_in[5];    // [2,E]
    const int*   batch  = (const int*)d_in[6];    // [N]

    const int n = in_sizes[0] / D;
    const int e = in_sizes[5] / 2;
    const int L = in_sizes[1] / (D * D);
    const int G = out_size;                       // [G,1] output

    const int* esrc = edge;
    const int* edst = edge + e;

    // workspace layout (256B aligned)
    char* ws = (char*)d_ws;
    size_t off = 0;
    auto alloc = [&](size_t bytes) -> void* {
        void* p = ws + off;
        off += (bytes + 255) & ~(size_t)255;
        return p;
    };
    int*   cnt       = (int*)alloc((size_t)n * 4);
    int*   row_start = (int*)alloc((size_t)(n + 1) * 4);
    int*   cursor    = (int*)alloc((size_t)n * 4);
    float* dinv      = (float*)alloc((size_t)n * 4);
    int*   csr_src   = (int*)alloc((size_t)e * 4);
    float* hbuf      = (float*)alloc((size_t)n * D * 4);
    float* xbuf      = (float*)alloc((size_t)n * D * 4);
    float* sums      = (float*)alloc((size_t)G * D * 4);
    int*   counts    = (int*)alloc((size_t)G * 4);
    (void)ws_size;

    hipMemsetAsync(cnt, 0, (size_t)n * 4, stream);
    hipMemsetAsync(sums, 0, (size_t)G * D * 4, stream);
    hipMemsetAsync(counts, 0, (size_t)G * 4, stream);

    // CSR build (by dst)
    hist_kernel<<<(e + 255) / 256, 256, 0, stream>>>(edst, cnt, e);
    scan_kernel<<<1, SCAN_THREADS, 0, stream>>>(cnt, row_start, cursor, dinv, n);
    scatter_kernel<<<(e + 255) / 256, 256, 0, stream>>>(esrc, edst, cursor, csr_src, e);

    // layers
    const float* xin = x;
    for (int l = 0; l < L; ++l) {
        matmul_kernel<<<(n + 31) / 32, 256, 0, stream>>>(xin, conv_W + (size_t)l * D * D, hbuf, n);
        agg_kernel<<<(n + 3) / 4, 256, 0, stream>>>(hbuf, csr_src, row_start, dinv,
                                                    conv_b + (size_t)l * D, xbuf, n);
        xin = xbuf;
    }

    // pool + final linear
    int waves = (n + POOL_CHUNK - 1) / POOL_CHUNK;
    pool_kernel<<<(waves + 3) / 4, 256, 0, stream>>>(xin, batch, sums, counts, n);
    final_kernel<<<G, 64, 0, stream>>>(sums, counts, lin_W, lin_b, (float*)d_out);
}

// Round 3
// 476.424 us; speedup vs baseline: 1.5548x; 1.5548x over previous
//
#include <hip/hip_runtime.h>

// GCN forward: 4 x (X@W -> gather-normalize-scatter -> +b, ReLU) -> mean pool -> linear
// N=50000 nodes, E=800000 edges, D=64, L=4, G=64.
// R3: parallel 3-pass scan kept; agg reverted to R1's proven sequential order but with
// 4x batched loads (same arithmetic order as R1 -> bitwise identical, 4x the MLP).

#define D 64
#define POOL_CHUNK 128

// ---- CSR build ----------------------------------------------------------

__global__ void hist_kernel(const int* __restrict__ dst, int* __restrict__ cnt, int e) {
    int i = blockIdx.x * blockDim.x + threadIdx.x;
    if (i < e) atomicAdd(&cnt[dst[i]], 1);
}

// pass1: per-block exclusive scan of cnt -> row_start (block-local), block totals,
// and dinv = 1/sqrt(deg+1) fused in.
__global__ __launch_bounds__(1024) void scan_pass1(
        const int* __restrict__ cnt, int* __restrict__ row_start,
        int* __restrict__ blocksum, float* __restrict__ dinv, int n) {
    __shared__ int sh[1024];
    int t = threadIdx.x;
    int i = blockIdx.x * 1024 + t;
    int c = (i < n) ? cnt[i] : 0;
    if (i < n) dinv[i] = 1.0f / sqrtf((float)(c + 1));
    sh[t] = c;
    __syncthreads();
    for (int off = 1; off < 1024; off <<= 1) {
        int vp = (t >= off) ? sh[t - off] : 0;
        __syncthreads();
        sh[t] += vp;
        __syncthreads();
    }
    if (i < n) row_start[i] = sh[t] - c;          // block-local exclusive prefix
    if (t == 1023) blocksum[blockIdx.x] = sh[1023];
}

// pass2: single block scans the (<=1024) block sums -> exclusive block offsets in place.
__global__ __launch_bounds__(1024) void scan_pass2(int* __restrict__ blocksum, int nb) {
    __shared__ int sh[1024];
    int t = threadIdx.x;
    int c = (t < nb) ? blocksum[t] : 0;
    sh[t] = c;
    __syncthreads();
    for (int off = 1; off < 1024; off <<= 1) {
        int vp = (t >= off) ? sh[t - off] : 0;
        __syncthreads();
        sh[t] += vp;
        __syncthreads();
    }
    if (t < nb) blocksum[t] = sh[t] - c;          // exclusive
}

// pass3: add block offsets; emit cursor copy; write row_start[n]=E.
__global__ __launch_bounds__(1024) void scan_pass3(
        int* __restrict__ row_start, const int* __restrict__ blocksum,
        int* __restrict__ cursor, int n, int e) {
    int i = blockIdx.x * 1024 + threadIdx.x;
    if (i < n) {
        int r = row_start[i] + blocksum[blockIdx.x];
        row_start[i] = r;
        cursor[i] = r;
    }
    if (i == 0) row_start[n] = e;
}

__global__ void scatter_kernel(const int* __restrict__ src, const int* __restrict__ dst,
                               int* __restrict__ cursor, int* __restrict__ csr_src, int e) {
    int i = blockIdx.x * blockDim.x + threadIdx.x;
    if (i < e) {
        int pos = atomicAdd(&cursor[dst[i]], 1);
        csr_src[pos] = src[i];
    }
}

// ---- per-layer: H = X @ W  (32 rows per 256-thread block) ---------------

__global__ __launch_bounds__(256) void matmul_kernel(
        const float* __restrict__ X, const float* __restrict__ W,
        float* __restrict__ H, int n) {
    __shared__ __align__(16) float Ws[D][D];   // 16 KB
    __shared__ __align__(16) float Xs[32][D];  // 8 KB
    int t = threadIdx.x;
    const float4* W4 = (const float4*)W;
    float4* Ws4 = (float4*)&Ws[0][0];
    #pragma unroll
    for (int i = t; i < D * D / 4; i += 256) Ws4[i] = W4[i];
    int rowBase = blockIdx.x * 32;
    const float4* X4 = (const float4*)X;
    float4* Xs4 = (float4*)&Xs[0][0];
    #pragma unroll
    for (int i = t; i < 32 * D / 4; i += 256) {
        int rl = i >> 4;
        int c4 = i & 15;
        int r = rowBase + rl;
        float4 v = make_float4(0.f, 0.f, 0.f, 0.f);
        if (r < n) v = X4[(size_t)r * (D / 4) + c4];
        Xs4[i] = v;
    }
    __syncthreads();
    int wave = t >> 6, lane = t & 63;
    int r0 = wave * 8;
    float acc[8] = {0.f, 0.f, 0.f, 0.f, 0.f, 0.f, 0.f, 0.f};
    #pragma unroll
    for (int k = 0; k < D; ++k) {
        float w = Ws[k][lane];
        #pragma unroll
        for (int j = 0; j < 8; ++j)
            acc[j] += Xs[r0 + j][k] * w;
    }
    #pragma unroll
    for (int j = 0; j < 8; ++j) {
        int r = rowBase + r0 + j;
        if (r < n) H[(size_t)r * D + lane] = acc[j];
    }
}

// ---- per-layer: aggregate + bias + ReLU (wave per node, lane per feat) --
// R1-exact arithmetic order; loads batched 4 edges at a time for MLP.

__global__ __launch_bounds__(256) void agg_kernel(
        const float* __restrict__ H, const int* __restrict__ csr_src,
        const int* __restrict__ row_start, const float* __restrict__ dinv,
        const float* __restrict__ bias, float* __restrict__ out, int n) {
    int wave = threadIdx.x >> 6, lane = threadIdx.x & 63;
    int v = blockIdx.x * 4 + wave;
    if (v >= n) return;
    float dv = dinv[v];
    float acc = dv * H[(size_t)v * D + lane];     // self-loop term (outer dv at end)
    int s = row_start[v];
    int e = row_start[v + 1];
    int i = s;
    #pragma unroll 1
    for (; i + 4 <= e; i += 4) {
        int u0 = csr_src[i + 0];
        int u1 = csr_src[i + 1];
        int u2 = csr_src[i + 2];
        int u3 = csr_src[i + 3];
        float w0 = dinv[u0], w1 = dinv[u1], w2 = dinv[u2], w3 = dinv[u3];
        float h0 = H[(size_t)u0 * D + lane];
        float h1 = H[(size_t)u1 * D + lane];
        float h2 = H[(size_t)u2 * D + lane];
        float h3 = H[(size_t)u3 * D + lane];
        acc += w0 * h0;
        acc += w1 * h1;
        acc += w2 * h2;
        acc += w3 * h3;
    }
    for (; i < e; ++i) {
        int u = csr_src[i];
        acc += dinv[u] * H[(size_t)u * D + lane];
    }
    out[(size_t)v * D + lane] = fmaxf(dv * acc + bias[lane], 0.f);
}

// ---- mean pool (batch sorted: accumulate in regs, flush on group change) -

__global__ __launch_bounds__(256) void pool_kernel(
        const float* __restrict__ X, const int* __restrict__ batch,
        float* __restrict__ sums, int* __restrict__ counts, int n) {
    int wave = threadIdx.x >> 6, lane = threadIdx.x & 63;
    int w = blockIdx.x * 4 + wave;
    int begin = w * POOL_CHUNK;
    if (begin >= n) return;
    int end = min(begin + POOL_CHUNK, n);
    int cur = batch[begin];
    float acc = 0.f;
    int cnt = 0;
    for (int v = begin; v < end; ++v) {
        int g = batch[v];
        if (g != cur) {
            atomicAdd(&sums[cur * D + lane], acc);
            if (lane == 0) atomicAdd(&counts[cur], cnt);
            acc = 0.f; cnt = 0; cur = g;
        }
        acc += X[(size_t)v * D + lane];
        ++cnt;
    }
    atomicAdd(&sums[cur * D + lane], acc);
    if (lane == 0) atomicAdd(&counts[cur], cnt);
}

__global__ void final_kernel(const float* __restrict__ sums, const int* __restrict__ counts,
                             const float* __restrict__ linW, const float* __restrict__ linb,
                             float* __restrict__ out) {
    int g = blockIdx.x;
    int lane = threadIdx.x;  // blockDim = 64
    float p = sums[g * D + lane] * linW[lane];
    #pragma unroll
    for (int off = 32; off > 0; off >>= 1) p += __shfl_down(p, off, 64);
    if (lane == 0) out[g] = p / fmaxf((float)counts[g], 1.f) + linb[0];
}

// ---- orchestration -------------------------------------------------------

extern "C" void kernel_launch(void* const* d_in, const int* in_sizes, int n_in,
                              void* d_out, int out_size, void* d_ws, size_t ws_size,
                              hipStream_t stream) {
    const float* x      = (const float*)d_in[0];  // [N,64]
    const float* conv_W = (const float*)d_in[1];  // [4,64,64]
    const float* conv_b = (const float*)d_in[2];  // [4,64]
    const float* lin_W  = (const float*)d_in[3];  // [64,1]
    const float* lin_b  = (const float*)d_in[4];  // [1]
    const int*   edge   = (const int*)d_in[5];    // [2,E]
    const int*   batch  = (const int*)d_in[6];    // [N]

    const int n = in_sizes[0] / D;
    const int e = in_sizes[5] / 2;
    const int L = in_sizes[1] / (D * D);
    const int G = out_size;

    const int* esrc = edge;
    const int* edst = edge + e;

    // workspace layout (256B aligned)
    char* ws = (char*)d_ws;
    size_t off = 0;
    auto alloc = [&](size_t bytes) -> void* {
        void* p = ws + off;
        off += (bytes + 255) & ~(size_t)255;
        return p;
    };
    const int nb = (n + 1023) / 1024;             // scan blocks (49)
    int*   cnt       = (int*)alloc((size_t)n * 4);
    int*   row_start = (int*)alloc((size_t)(n + 1) * 4);
    int*   cursor    = (int*)alloc((size_t)n * 4);
    float* dinv      = (float*)alloc((size_t)n * 4);
    int*   blocksum  = (int*)alloc((size_t)nb * 4);
    int*   csr_src   = (int*)alloc((size_t)e * 4);
    float* hbuf      = (float*)alloc((size_t)n * D * 4);
    float* xbuf      = (float*)alloc((size_t)n * D * 4);
    float* sums      = (float*)alloc((size_t)G * D * 4);
    int*   counts    = (int*)alloc((size_t)G * 4);
    (void)ws_size;

    hipMemsetAsync(cnt, 0, (size_t)n * 4, stream);
    hipMemsetAsync(sums, 0, (size_t)G * D * 4, stream);
    hipMemsetAsync(counts, 0, (size_t)G * 4, stream);

    // CSR build (by dst)
    hist_kernel<<<(e + 255) / 256, 256, 0, stream>>>(edst, cnt, e);
    scan_pass1<<<nb, 1024, 0, stream>>>(cnt, row_start, blocksum, dinv, n);
    scan_pass2<<<1, 1024, 0, stream>>>(blocksum, nb);
    scan_pass3<<<nb, 1024, 0, stream>>>(row_start, blocksum, cursor, n, e);
    scatter_kernel<<<(e + 255) / 256, 256, 0, stream>>>(esrc, edst, cursor, csr_src, e);

    // layers
    const float* xin = x;
    for (int l = 0; l < L; ++l) {
        matmul_kernel<<<(n + 31) / 32, 256, 0, stream>>>(xin, conv_W + (size_t)l * D * D, hbuf, n);
        agg_kernel<<<(n + 3) / 4, 256, 0, stream>>>(hbuf, csr_src, row_start, dinv,
                                                    conv_b + (size_t)l * D, xbuf, n);
        xin = xbuf;
    }

    // pool + final linear
    int waves = (n + POOL_CHUNK - 1) / POOL_CHUNK;
    pool_kernel<<<(waves + 3) / 4, 256, 0, stream>>>(xin, batch, sums, counts, n);
    final_kernel<<<G, 64, 0, stream>>>(sums, counts, lin_W, lin_b, (float*)d_out);
}

// Round 4
// 424.381 us; speedup vs baseline: 1.7455x; 1.1226x over previous
//
#include <hip/hip_runtime.h>

// GCN forward: 4 x (X@W -> gather-normalize-scatter -> +b, ReLU) -> mean pool -> linear
// N=50000 nodes, E=800000 edges, D=64, L=4, G=64.
// R4: bucket-partitioned CSR build. R3's scatter wrote 52MB to HBM (16x amplification:
// random 4B writes, cross-XCD line bouncing). Now: edges partitioned by dst>>10 into
// ~49 buckets (LDS binning, block-bulk reservations), then one block PER BUCKET does
// node-hist + local scan + scatter with LDS cursors -> each bucket's 65KB csr region is
// single-XCD, L2-resident, written back once. Bucket scan doubles as the global row
// scan (bucket edge count == sum of node degrees), killing hist/scan_pass1-3 entirely.
// agg keeps R3's bitwise arithmetic order, unrolled 8-wide.
// NOTE: edge record packs src (<65536, ok for N=50000) | (dst&1023)<<16 into 4B.

#define D 64
#define POOL_CHUNK 128
#define BSHIFT 10                 // nodes per bucket = 1024
#define BNODES 1024
#define EPT 16                    // edges per thread in partition kernels
#define CB (256 * EPT)            // edges per block = 4096

// ---- CSR build: bucket partition ----------------------------------------

__global__ __launch_bounds__(256) void bucket_hist(
        const int* __restrict__ dst, int* __restrict__ bcnt, int e) {
    __shared__ int c[256];
    int t = threadIdx.x;
    c[t] = 0;
    __syncthreads();
    int base = blockIdx.x * CB;
    #pragma unroll
    for (int k = 0; k < EPT; ++k) {
        int i = base + t + k * 256;
        if (i < e) atomicAdd(&c[dst[i] >> BSHIFT], 1);
    }
    __syncthreads();
    if (c[t]) atomicAdd(&bcnt[t], c[t]);
}

// single block: exclusive scan of bucket counts -> boff; init bcur; row_start[n]=e.
__global__ __launch_bounds__(256) void bucket_scan(
        const int* __restrict__ bcnt, int* __restrict__ boff, int* __restrict__ bcur,
        int* __restrict__ row_start, int n, int e, int nb) {
    __shared__ int sh[256];
    int t = threadIdx.x;
    int c = (t < nb) ? bcnt[t] : 0;
    sh[t] = c;
    __syncthreads();
    for (int off = 1; off < 256; off <<= 1) {
        int vp = (t >= off) ? sh[t - off] : 0;
        __syncthreads();
        sh[t] += vp;
        __syncthreads();
    }
    int excl = sh[t] - c;
    if (t < nb) { boff[t] = excl; bcur[t] = excl; }
    if (t == 255) boff[nb] = sh[255];   // == e
    if (t == 0) row_start[n] = e;
}

// partition edges into bucket-contiguous eb[] (packed: src | (dst&1023)<<16).
__global__ __launch_bounds__(256) void bucket_scatter(
        const int* __restrict__ src, const int* __restrict__ dst,
        int* __restrict__ bcur, unsigned* __restrict__ eb, int e) {
    __shared__ int cB[256], gb[256], cur[256];
    int t = threadIdx.x;
    cB[t] = 0;
    __syncthreads();
    int base = blockIdx.x * CB;
    int ps[EPT], pd[EPT];
    #pragma unroll
    for (int k = 0; k < EPT; ++k) {
        int i = base + t + k * 256;
        if (i < e) {
            ps[k] = src[i];
            pd[k] = dst[i];
            atomicAdd(&cB[pd[k] >> BSHIFT], 1);
        } else {
            pd[k] = -1;
        }
    }
    __syncthreads();
    if (cB[t]) gb[t] = atomicAdd(&bcur[t], cB[t]);
    cur[t] = 0;
    __syncthreads();
    #pragma unroll
    for (int k = 0; k < EPT; ++k) {
        if (pd[k] >= 0) {
            int b = pd[k] >> BSHIFT;
            int p = atomicAdd(&cur[b], 1);
            eb[gb[b] + p] = (unsigned)(ps[k] & 0xFFFF) | ((unsigned)(pd[k] & (BNODES - 1)) << 16);
        }
    }
}

// one block per bucket: node degree hist (LDS atomics) + local exclusive scan + dinv.
__global__ __launch_bounds__(BNODES) void node_hist_scan(
        const unsigned* __restrict__ eb, const int* __restrict__ boff,
        int* __restrict__ rs_local, float* __restrict__ dinv, int n) {
    __shared__ int sh[BNODES];
    int b = blockIdx.x, t = threadIdx.x;
    int s = boff[b], e2 = boff[b + 1];
    sh[t] = 0;
    __syncthreads();
    for (int i = s + t; i < e2; i += BNODES) atomicAdd(&sh[eb[i] >> 16], 1);
    __syncthreads();
    int c = sh[t];
    __syncthreads();
    for (int off = 1; off < BNODES; off <<= 1) {
        int vp = (t >= off) ? sh[t - off] : 0;
        __syncthreads();
        sh[t] += vp;
        __syncthreads();
    }
    int node = b * BNODES + t;
    if (node < n) {
        rs_local[node] = sh[t] - c;   // bucket-local exclusive prefix
        dinv[node] = 1.0f / sqrtf((float)(c + 1));
    }
}

// one block per bucket: absolute row_start + LDS-cursor scatter (csr region is
// single-XCD, L2-resident; written back once as full lines).
__global__ __launch_bounds__(BNODES) void final_scatter(
        const unsigned* __restrict__ eb, const int* __restrict__ boff,
        const int* __restrict__ rs_local, int* __restrict__ row_start,
        int* __restrict__ csr_src, int n) {
    __shared__ int cur[BNODES];
    int b = blockIdx.x, t = threadIdx.x;
    int s = boff[b], e2 = boff[b + 1];
    int node = b * BNODES + t;
    int a = 0;
    if (node < n) {
        a = rs_local[node] + s;       // absolute row offset
        row_start[node] = a;
    }
    cur[t] = a;
    __syncthreads();
    for (int i = s + t; i < e2; i += BNODES) {
        unsigned v = eb[i];
        int p = atomicAdd(&cur[v >> 16], 1);
        csr_src[p] = (int)(v & 0xFFFFu);
    }
}

// ---- per-layer: H = X @ W  (32 rows per 256-thread block) ---------------

__global__ __launch_bounds__(256) void matmul_kernel(
        const float* __restrict__ X, const float* __restrict__ W,
        float* __restrict__ H, int n) {
    __shared__ __align__(16) float Ws[D][D];   // 16 KB
    __shared__ __align__(16) float Xs[32][D];  // 8 KB
    int t = threadIdx.x;
    const float4* W4 = (const float4*)W;
    float4* Ws4 = (float4*)&Ws[0][0];
    #pragma unroll
    for (int i = t; i < D * D / 4; i += 256) Ws4[i] = W4[i];
    int rowBase = blockIdx.x * 32;
    const float4* X4 = (const float4*)X;
    float4* Xs4 = (float4*)&Xs[0][0];
    #pragma unroll
    for (int i = t; i < 32 * D / 4; i += 256) {
        int rl = i >> 4;
        int c4 = i & 15;
        int r = rowBase + rl;
        float4 v = make_float4(0.f, 0.f, 0.f, 0.f);
        if (r < n) v = X4[(size_t)r * (D / 4) + c4];
        Xs4[i] = v;
    }
    __syncthreads();
    int wave = t >> 6, lane = t & 63;
    int r0 = wave * 8;
    float acc[8] = {0.f, 0.f, 0.f, 0.f, 0.f, 0.f, 0.f, 0.f};
    #pragma unroll
    for (int k = 0; k < D; ++k) {
        float w = Ws[k][lane];
        #pragma unroll
        for (int j = 0; j < 8; ++j)
            acc[j] += Xs[r0 + j][k] * w;
    }
    #pragma unroll
    for (int j = 0; j < 8; ++j) {
        int r = rowBase + r0 + j;
        if (r < n) H[(size_t)r * D + lane] = acc[j];
    }
}

// ---- per-layer: aggregate + bias + ReLU (wave per node, lane per feat) --
// R3-exact arithmetic order; loads batched 8 edges at a time for MLP.

__global__ __launch_bounds__(256) void agg_kernel(
        const float* __restrict__ H, const int* __restrict__ csr_src,
        const int* __restrict__ row_start, const float* __restrict__ dinv,
        const float* __restrict__ bias, float* __restrict__ out, int n) {
    int wave = threadIdx.x >> 6, lane = threadIdx.x & 63;
    int v = blockIdx.x * 4 + wave;
    if (v >= n) return;
    float dv = dinv[v];
    float acc = dv * H[(size_t)v * D + lane];     // self-loop term (outer dv at end)
    int s = row_start[v];
    int e = row_start[v + 1];
    int i = s;
    #pragma unroll 1
    for (; i + 8 <= e; i += 8) {
        int u0 = csr_src[i + 0], u1 = csr_src[i + 1];
        int u2 = csr_src[i + 2], u3 = csr_src[i + 3];
        int u4 = csr_src[i + 4], u5 = csr_src[i + 5];
        int u6 = csr_src[i + 6], u7 = csr_src[i + 7];
        float w0 = dinv[u0], w1 = dinv[u1], w2 = dinv[u2], w3 = dinv[u3];
        float w4 = dinv[u4], w5 = dinv[u5], w6 = dinv[u6], w7 = dinv[u7];
        float h0 = H[(size_t)u0 * D + lane];
        float h1 = H[(size_t)u1 * D + lane];
        float h2 = H[(size_t)u2 * D + lane];
        float h3 = H[(size_t)u3 * D + lane];
        float h4 = H[(size_t)u4 * D + lane];
        float h5 = H[(size_t)u5 * D + lane];
        float h6 = H[(size_t)u6 * D + lane];
        float h7 = H[(size_t)u7 * D + lane];
        acc += w0 * h0;
        acc += w1 * h1;
        acc += w2 * h2;
        acc += w3 * h3;
        acc += w4 * h4;
        acc += w5 * h5;
        acc += w6 * h6;
        acc += w7 * h7;
    }
    for (; i < e; ++i) {
        int u = csr_src[i];
        acc += dinv[u] * H[(size_t)u * D + lane];
    }
    out[(size_t)v * D + lane] = fmaxf(dv * acc + bias[lane], 0.f);
}

// ---- mean pool (batch sorted: accumulate in regs, flush on group change) -

__global__ __launch_bounds__(256) void pool_kernel(
        const float* __restrict__ X, const int* __restrict__ batch,
        float* __restrict__ sums, int* __restrict__ counts, int n) {
    int wave = threadIdx.x >> 6, lane = threadIdx.x & 63;
    int w = blockIdx.x * 4 + wave;
    int begin = w * POOL_CHUNK;
    if (begin >= n) return;
    int end = min(begin + POOL_CHUNK, n);
    int cur = batch[begin];
    float acc = 0.f;
    int cnt = 0;
    for (int v = begin; v < end; ++v) {
        int g = batch[v];
        if (g != cur) {
            atomicAdd(&sums[cur * D + lane], acc);
            if (lane == 0) atomicAdd(&counts[cur], cnt);
            acc = 0.f; cnt = 0; cur = g;
        }
        acc += X[(size_t)v * D + lane];
        ++cnt;
    }
    atomicAdd(&sums[cur * D + lane], acc);
    if (lane == 0) atomicAdd(&counts[cur], cnt);
}

__global__ void final_kernel(const float* __restrict__ sums, const int* __restrict__ counts,
                             const float* __restrict__ linW, const float* __restrict__ linb,
                             float* __restrict__ out) {
    int g = blockIdx.x;
    int lane = threadIdx.x;  // blockDim = 64
    float p = sums[g * D + lane] * linW[lane];
    #pragma unroll
    for (int off = 32; off > 0; off >>= 1) p += __shfl_down(p, off, 64);
    if (lane == 0) out[g] = p / fmaxf((float)counts[g], 1.f) + linb[0];
}

// ---- orchestration -------------------------------------------------------

extern "C" void kernel_launch(void* const* d_in, const int* in_sizes, int n_in,
                              void* d_out, int out_size, void* d_ws, size_t ws_size,
                              hipStream_t stream) {
    const float* x      = (const float*)d_in[0];  // [N,64]
    const float* conv_W = (const float*)d_in[1];  // [4,64,64]
    const float* conv_b = (const float*)d_in[2];  // [4,64]
    const float* lin_W  = (const float*)d_in[3];  // [64,1]
    const float* lin_b  = (const float*)d_in[4];  // [1]
    const int*   edge   = (const int*)d_in[5];    // [2,E]
    const int*   batch  = (const int*)d_in[6];    // [N]

    const int n = in_sizes[0] / D;
    const int e = in_sizes[5] / 2;
    const int L = in_sizes[1] / (D * D);
    const int G = out_size;

    const int* esrc = edge;
    const int* edst = edge + e;

    // workspace layout (256B aligned)
    char* ws = (char*)d_ws;
    size_t off = 0;
    auto alloc = [&](size_t bytes) -> void* {
        void* p = ws + off;
        off += (bytes + 255) & ~(size_t)255;
        return p;
    };
    const int nb = (n + BNODES - 1) / BNODES;     // buckets (49)
    int*   bcnt      = (int*)alloc(256 * 4);
    int*   boff      = (int*)alloc(257 * 4);
    int*   bcur      = (int*)alloc(256 * 4);
    int*   rs_local  = (int*)alloc((size_t)n * 4);
    float* dinv      = (float*)alloc((size_t)n * 4);
    int*   row_start = (int*)alloc((size_t)(n + 1) * 4);
    int*   csr_src   = (int*)alloc((size_t)e * 4);
    float* hbuf      = (float*)alloc((size_t)n * D * 4);
    float* xbuf      = (float*)alloc((size_t)n * D * 4);
    float* sums      = (float*)alloc((size_t)G * D * 4);
    int*   counts    = (int*)alloc((size_t)G * 4);
    unsigned* eb     = (unsigned*)hbuf;           // alias: eb dead before matmul L0 writes hbuf
    (void)ws_size;

    hipMemsetAsync(bcnt, 0, 256 * 4, stream);
    hipMemsetAsync(sums, 0, (size_t)G * D * 4, stream);
    hipMemsetAsync(counts, 0, (size_t)G * 4, stream);

    const int pb = (e + CB - 1) / CB;             // partition blocks (196)
    bucket_hist   <<<pb, 256, 0, stream>>>(edst, bcnt, e);
    bucket_scan   <<<1, 256, 0, stream>>>(bcnt, boff, bcur, row_start, n, e, nb);
    bucket_scatter<<<pb, 256, 0, stream>>>(esrc, edst, bcur, eb, e);
    node_hist_scan<<<nb, BNODES, 0, stream>>>(eb, boff, rs_local, dinv, n);
    final_scatter <<<nb, BNODES, 0, stream>>>(eb, boff, rs_local, row_start, csr_src, n);

    // layers
    const float* xin = x;
    for (int l = 0; l < L; ++l) {
        matmul_kernel<<<(n + 31) / 32, 256, 0, stream>>>(xin, conv_W + (size_t)l * D * D, hbuf, n);
        agg_kernel<<<(n + 3) / 4, 256, 0, stream>>>(hbuf, csr_src, row_start, dinv,
                                                    conv_b + (size_t)l * D, xbuf, n);
        xin = xbuf;
    }

    // pool + final linear
    int waves = (n + POOL_CHUNK - 1) / POOL_CHUNK;
    pool_kernel<<<(waves + 3) / 4, 256, 0, stream>>>(xin, batch, sums, counts, n);
    final_kernel<<<G, 64, 0, stream>>>(sums, counts, lin_W, lin_b, (float*)d_out);
}

// Round 5
// 293.817 us; speedup vs baseline: 2.5211x; 1.4444x over previous
//
#include <hip/hip_runtime.h>

// GCN forward: 4 x (X@W -> gather-normalize-scatter -> +b, ReLU) -> mean pool -> linear
// N=50000 nodes, E=800000 edges, D=64, L=4, G=64.
// R5: matmul rebuilt as 4x4 register-tiled outer product (64 FMA per 8 ds_read_b128,
// XOR-swizzled LDS, W pre-transposed once) -- R4's was LDS-issue-bound at 256 VGPR /
// 8% occupancy. pool rebuilt around binary-searched group bounds (batch is sorted):
// 4 blocks/graph, one atomic flush per block (was 391 latency-bound waves, 47us).
// agg + CSR build unchanged (bitwise-proven).

#define D 64
#define BSHIFT 10                 // nodes per bucket = 1024
#define BNODES 1024
#define EPT 16                    // edges per thread in partition kernels
#define CB (256 * EPT)            // edges per block = 4096
#define SW(r, c4) ((c4) ^ (((r) >> 2) & 15))

// ---- CSR build: bucket partition ----------------------------------------

__global__ __launch_bounds__(256) void bucket_hist(
        const int* __restrict__ dst, int* __restrict__ bcnt, int e) {
    __shared__ int c[256];
    int t = threadIdx.x;
    c[t] = 0;
    __syncthreads();
    int base = blockIdx.x * CB;
    #pragma unroll
    for (int k = 0; k < EPT; ++k) {
        int i = base + t + k * 256;
        if (i < e) atomicAdd(&c[dst[i] >> BSHIFT], 1);
    }
    __syncthreads();
    if (c[t]) atomicAdd(&bcnt[t], c[t]);
}

__global__ __launch_bounds__(256) void bucket_scan(
        const int* __restrict__ bcnt, int* __restrict__ boff, int* __restrict__ bcur,
        int* __restrict__ row_start, int n, int e, int nb) {
    __shared__ int sh[256];
    int t = threadIdx.x;
    int c = (t < nb) ? bcnt[t] : 0;
    sh[t] = c;
    __syncthreads();
    for (int off = 1; off < 256; off <<= 1) {
        int vp = (t >= off) ? sh[t - off] : 0;
        __syncthreads();
        sh[t] += vp;
        __syncthreads();
    }
    int excl = sh[t] - c;
    if (t < nb) { boff[t] = excl; bcur[t] = excl; }
    if (t == 255) boff[nb] = sh[255];   // == e
    if (t == 0) row_start[n] = e;
}

__global__ __launch_bounds__(256) void bucket_scatter(
        const int* __restrict__ src, const int* __restrict__ dst,
        int* __restrict__ bcur, unsigned* __restrict__ eb, int e) {
    __shared__ int cB[256], gb[256], cur[256];
    int t = threadIdx.x;
    cB[t] = 0;
    __syncthreads();
    int base = blockIdx.x * CB;
    int ps[EPT], pd[EPT];
    #pragma unroll
    for (int k = 0; k < EPT; ++k) {
        int i = base + t + k * 256;
        if (i < e) {
            ps[k] = src[i];
            pd[k] = dst[i];
            atomicAdd(&cB[pd[k] >> BSHIFT], 1);
        } else {
            pd[k] = -1;
        }
    }
    __syncthreads();
    if (cB[t]) gb[t] = atomicAdd(&bcur[t], cB[t]);
    cur[t] = 0;
    __syncthreads();
    #pragma unroll
    for (int k = 0; k < EPT; ++k) {
        if (pd[k] >= 0) {
            int b = pd[k] >> BSHIFT;
            int p = atomicAdd(&cur[b], 1);
            eb[gb[b] + p] = (unsigned)(ps[k] & 0xFFFF) | ((unsigned)(pd[k] & (BNODES - 1)) << 16);
        }
    }
}

__global__ __launch_bounds__(BNODES) void node_hist_scan(
        const unsigned* __restrict__ eb, const int* __restrict__ boff,
        int* __restrict__ rs_local, float* __restrict__ dinv, int n) {
    __shared__ int sh[BNODES];
    int b = blockIdx.x, t = threadIdx.x;
    int s = boff[b], e2 = boff[b + 1];
    sh[t] = 0;
    __syncthreads();
    for (int i = s + t; i < e2; i += BNODES) atomicAdd(&sh[eb[i] >> 16], 1);
    __syncthreads();
    int c = sh[t];
    __syncthreads();
    for (int off = 1; off < BNODES; off <<= 1) {
        int vp = (t >= off) ? sh[t - off] : 0;
        __syncthreads();
        sh[t] += vp;
        __syncthreads();
    }
    int node = b * BNODES + t;
    if (node < n) {
        rs_local[node] = sh[t] - c;
        dinv[node] = 1.0f / sqrtf((float)(c + 1));
    }
}

__global__ __launch_bounds__(BNODES) void final_scatter(
        const unsigned* __restrict__ eb, const int* __restrict__ boff,
        const int* __restrict__ rs_local, int* __restrict__ row_start,
        int* __restrict__ csr_src, int n) {
    __shared__ int cur[BNODES];
    int b = blockIdx.x, t = threadIdx.x;
    int s = boff[b], e2 = boff[b + 1];
    int node = b * BNODES + t;
    int a = 0;
    if (node < n) {
        a = rs_local[node] + s;
        row_start[node] = a;
    }
    cur[t] = a;
    __syncthreads();
    for (int i = s + t; i < e2; i += BNODES) {
        unsigned v = eb[i];
        int p = atomicAdd(&cur[v >> 16], 1);
        csr_src[p] = (int)(v & 0xFFFFu);
    }
}

// ---- W transpose (once, all layers): Wt[l][c][k] = W[l][k][c] ------------

__global__ __launch_bounds__(256) void wtrans_kernel(
        const float* __restrict__ W, float* __restrict__ Wt) {
    int l = blockIdx.x;
    const float* w = W + (size_t)l * D * D;
    float* wt = Wt + (size_t)l * D * D;
    for (int idx = threadIdx.x; idx < D * D; idx += 256) {
        int k = idx >> 6, c = idx & 63;
        wt[c * D + k] = w[idx];
    }
}

// ---- per-layer: H = X @ W, 4x4 register tile, swizzled LDS --------------
// Block: 64 rows x 64 cols. Wave wv: cols [wv*16, wv*16+16). Lane: rg=lane>>2
// rows 4rg..4rg+3, cg=lane&3 cols 4cg..4cg+3. Per k4-step: 8 ds_read_b128 -> 64 FMA.
// k accumulation order is sequential 0..63 (bitwise-identical to R4's matmul).

__global__ __launch_bounds__(256, 3) void matmul_kernel(
        const float* __restrict__ X, const float* __restrict__ Wt,
        float* __restrict__ H, int n) {
    __shared__ float4 Xs[64 * 16];   // 16 KB, swizzled
    __shared__ float4 Ws[64 * 16];   // 16 KB, swizzled (Wt rows = W cols)
    int t = threadIdx.x;
    int rowBase = blockIdx.x * 64;
    const float4* X4 = (const float4*)X;
    const float4* Wt4 = (const float4*)Wt;
    #pragma unroll
    for (int p = 0; p < 4; ++p) {
        int rl = (t >> 4) + 16 * p;
        int c4 = t & 15;
        int r = rowBase + rl;
        float4 v = make_float4(0.f, 0.f, 0.f, 0.f);
        if (r < n) v = X4[(size_t)r * 16 + c4];
        Xs[rl * 16 + SW(rl, c4)] = v;
        Ws[rl * 16 + SW(rl, c4)] = Wt4[rl * 16 + c4];
    }
    __syncthreads();
    int wv = t >> 6, lane = t & 63;
    int rg = lane >> 2, cg = lane & 3;
    int r0 = rg * 4;
    int c0 = wv * 16 + cg * 4;
    float acc[4][4] = {};
    #pragma unroll 2
    for (int k4 = 0; k4 < 16; ++k4) {
        float4 xv[4], wvv[4];
        #pragma unroll
        for (int i = 0; i < 4; ++i) xv[i] = Xs[(r0 + i) * 16 + SW(r0 + i, k4)];
        #pragma unroll
        for (int j = 0; j < 4; ++j) wvv[j] = Ws[(c0 + j) * 16 + SW(c0 + j, k4)];
        #pragma unroll
        for (int i = 0; i < 4; ++i)
            #pragma unroll
            for (int j = 0; j < 4; ++j) {
                acc[i][j] += xv[i].x * wvv[j].x;
                acc[i][j] += xv[i].y * wvv[j].y;
                acc[i][j] += xv[i].z * wvv[j].z;
                acc[i][j] += xv[i].w * wvv[j].w;
            }
    }
    #pragma unroll
    for (int i = 0; i < 4; ++i) {
        int r = rowBase + r0 + i;
        if (r < n) {
            float4 o = make_float4(acc[i][0], acc[i][1], acc[i][2], acc[i][3]);
            *(float4*)&H[(size_t)r * D + c0] = o;
        }
    }
}

// ---- per-layer: aggregate + bias + ReLU (wave per node, lane per feat) --
// R4-exact arithmetic order; loads batched 8 edges at a time for MLP.

__global__ __launch_bounds__(256) void agg_kernel(
        const float* __restrict__ H, const int* __restrict__ csr_src,
        const int* __restrict__ row_start, const float* __restrict__ dinv,
        const float* __restrict__ bias, float* __restrict__ out, int n) {
    int wave = threadIdx.x >> 6, lane = threadIdx.x & 63;
    int v = blockIdx.x * 4 + wave;
    if (v >= n) return;
    float dv = dinv[v];
    float acc = dv * H[(size_t)v * D + lane];
    int s = row_start[v];
    int e = row_start[v + 1];
    int i = s;
    #pragma unroll 1
    for (; i + 8 <= e; i += 8) {
        int u0 = csr_src[i + 0], u1 = csr_src[i + 1];
        int u2 = csr_src[i + 2], u3 = csr_src[i + 3];
        int u4 = csr_src[i + 4], u5 = csr_src[i + 5];
        int u6 = csr_src[i + 6], u7 = csr_src[i + 7];
        float w0 = dinv[u0], w1 = dinv[u1], w2 = dinv[u2], w3 = dinv[u3];
        float w4 = dinv[u4], w5 = dinv[u5], w6 = dinv[u6], w7 = dinv[u7];
        float h0 = H[(size_t)u0 * D + lane];
        float h1 = H[(size_t)u1 * D + lane];
        float h2 = H[(size_t)u2 * D + lane];
        float h3 = H[(size_t)u3 * D + lane];
        float h4 = H[(size_t)u4 * D + lane];
        float h5 = H[(size_t)u5 * D + lane];
        float h6 = H[(size_t)u6 * D + lane];
        float h7 = H[(size_t)u7 * D + lane];
        acc += w0 * h0;
        acc += w1 * h1;
        acc += w2 * h2;
        acc += w3 * h3;
        acc += w4 * h4;
        acc += w5 * h5;
        acc += w6 * h6;
        acc += w7 * h7;
    }
    for (; i < e; ++i) {
        int u = csr_src[i];
        acc += dinv[u] * H[(size_t)u * D + lane];
    }
    out[(size_t)v * D + lane] = fmaxf(dv * acc + bias[lane], 0.f);
}

// ---- mean pool: batch sorted -> binary-search group bounds ---------------

__device__ __forceinline__ int lower_bound_g(const int* __restrict__ b, int n, int g) {
    int lo = 0, hi = n;
    while (lo < hi) { int m = (lo + hi) >> 1; if (b[m] < g) lo = m + 1; else hi = m; }
    return lo;
}

// 4 blocks per graph; one atomic flush per block.
__global__ __launch_bounds__(256) void pool_kernel(
        const float* __restrict__ X, const int* __restrict__ batch,
        float* __restrict__ sums, int n) {
    __shared__ float sh[4][64];
    int g = blockIdx.x >> 2, part = blockIdx.x & 3;
    int gs = lower_bound_g(batch, n, g);
    int ge = lower_bound_g(batch, n, g + 1);
    int wv = threadIdx.x >> 6, lane = threadIdx.x & 63;
    int widx = part * 4 + wv;   // 0..15 waves across the graph
    float acc = 0.f;
    for (int r = gs + widx; r < ge; r += 16)
        acc += X[(size_t)r * D + lane];
    sh[wv][lane] = acc;
    __syncthreads();
    if (wv == 0) {
        float tot = (sh[0][lane] + sh[1][lane]) + (sh[2][lane] + sh[3][lane]);
        atomicAdd(&sums[g * D + lane], tot);
    }
}

__global__ void final_kernel(const float* __restrict__ sums, const int* __restrict__ batch,
                             const float* __restrict__ linW, const float* __restrict__ linb,
                             float* __restrict__ out, int n) {
    int g = blockIdx.x;
    int lane = threadIdx.x;  // blockDim = 64
    int gs = lower_bound_g(batch, n, g);
    int ge = lower_bound_g(batch, n, g + 1);
    float cnt = fmaxf((float)(ge - gs), 1.f);
    float p = (sums[g * D + lane] / cnt) * linW[lane];   // ref order: pool then dot
    #pragma unroll
    for (int off = 32; off > 0; off >>= 1) p += __shfl_down(p, off, 64);
    if (lane == 0) out[g] = p + linb[0];
}

// ---- orchestration -------------------------------------------------------

extern "C" void kernel_launch(void* const* d_in, const int* in_sizes, int n_in,
                              void* d_out, int out_size, void* d_ws, size_t ws_size,
                              hipStream_t stream) {
    const float* x      = (const float*)d_in[0];  // [N,64]
    const float* conv_W = (const float*)d_in[1];  // [4,64,64]
    const float* conv_b = (const float*)d_in[2];  // [4,64]
    const float* lin_W  = (const float*)d_in[3];  // [64,1]
    const float* lin_b  = (const float*)d_in[4];  // [1]
    const int*   edge   = (const int*)d_in[5];    // [2,E]
    const int*   batch  = (const int*)d_in[6];    // [N]

    const int n = in_sizes[0] / D;
    const int e = in_sizes[5] / 2;
    const int L = in_sizes[1] / (D * D);
    const int G = out_size;

    const int* esrc = edge;
    const int* edst = edge + e;

    // workspace layout (256B aligned)
    char* ws = (char*)d_ws;
    size_t off = 0;
    auto alloc = [&](size_t bytes) -> void* {
        void* p = ws + off;
        off += (bytes + 255) & ~(size_t)255;
        return p;
    };
    const int nb = (n + BNODES - 1) / BNODES;     // buckets (49)
    int*   bcnt      = (int*)alloc(256 * 4);
    int*   boff      = (int*)alloc(257 * 4);
    int*   bcur      = (int*)alloc(256 * 4);
    int*   rs_local  = (int*)alloc((size_t)n * 4);
    float* dinv      = (float*)alloc((size_t)n * 4);
    int*   row_start = (int*)alloc((size_t)(n + 1) * 4);
    int*   csr_src   = (int*)alloc((size_t)e * 4);
    float* wtbuf     = (float*)alloc((size_t)L * D * D * 4);
    float* hbuf      = (float*)alloc((size_t)n * D * 4);
    float* xbuf      = (float*)alloc((size_t)n * D * 4);
    float* sums      = (float*)alloc((size_t)G * D * 4);
    unsigned* eb     = (unsigned*)hbuf;           // alias: eb dead before matmul L0 writes hbuf
    (void)ws_size;

    hipMemsetAsync(bcnt, 0, 256 * 4, stream);
    hipMemsetAsync(sums, 0, (size_t)G * D * 4, stream);

    const int pb = (e + CB - 1) / CB;             // partition blocks (196)
    bucket_hist   <<<pb, 256, 0, stream>>>(edst, bcnt, e);
    bucket_scan   <<<1, 256, 0, stream>>>(bcnt, boff, bcur, row_start, n, e, nb);
    bucket_scatter<<<pb, 256, 0, stream>>>(esrc, edst, bcur, eb, e);
    node_hist_scan<<<nb, BNODES, 0, stream>>>(eb, boff, rs_local, dinv, n);
    final_scatter <<<nb, BNODES, 0, stream>>>(eb, boff, rs_local, row_start, csr_src, n);
    wtrans_kernel <<<L, 256, 0, stream>>>(conv_W, wtbuf);

    // layers
    const float* xin = x;
    for (int l = 0; l < L; ++l) {
        matmul_kernel<<<(n + 63) / 64, 256, 0, stream>>>(xin, wtbuf + (size_t)l * D * D, hbuf, n);
        agg_kernel<<<(n + 3) / 4, 256, 0, stream>>>(hbuf, csr_src, row_start, dinv,
                                                    conv_b + (size_t)l * D, xbuf, n);
        xin = xbuf;
    }

    // pool + final linear
    pool_kernel<<<G * 4, 256, 0, stream>>>(xin, batch, sums, n);
    final_kernel<<<G, 64, 0, stream>>>(sums, batch, lin_W, lin_b, (float*)d_out, n);
}

// Round 6
// 290.329 us; speedup vs baseline: 2.5514x; 1.0120x over previous
//
#include <hip/hip_runtime.h>

// GCN forward: 4 x (X@W -> gather-normalize-scatter -> +b, ReLU) -> mean pool -> linear
// N=50000 nodes, E=800000 edges, D=64, L=4, G=64.
// R6: (1) hipMemsetAsync -> custom zero_kernel (runtime fillBuffer was 43us per fill
// in-graph, top of profile). (2) matmul epilogue pre-scales H by dinv[row], so agg
// reads only H'[u] rows (no per-edge dinv gather) -- same multiplies, same order,
// bitwise identical to R5. CSR build / pool / final unchanged.

#define D 64
#define BSHIFT 10                 // nodes per bucket = 1024
#define BNODES 1024
#define EPT 16                    // edges per thread in partition kernels
#define CB (256 * EPT)            // edges per block = 4096
#define SW(r, c4) ((c4) ^ (((r) >> 2) & 15))

// ---- fused zeroing (replaces hipMemsetAsync fills) -----------------------

__global__ __launch_bounds__(256) void zero_kernel(
        int* __restrict__ bcnt, float* __restrict__ sums, int nsums) {
    int i = blockIdx.x * 256 + threadIdx.x;
    if (i < 256) bcnt[i] = 0;
    if (i < nsums) sums[i] = 0.f;
}

// ---- CSR build: bucket partition ----------------------------------------

__global__ __launch_bounds__(256) void bucket_hist(
        const int* __restrict__ dst, int* __restrict__ bcnt, int e) {
    __shared__ int c[256];
    int t = threadIdx.x;
    c[t] = 0;
    __syncthreads();
    int base = blockIdx.x * CB;
    #pragma unroll
    for (int k = 0; k < EPT; ++k) {
        int i = base + t + k * 256;
        if (i < e) atomicAdd(&c[dst[i] >> BSHIFT], 1);
    }
    __syncthreads();
    if (c[t]) atomicAdd(&bcnt[t], c[t]);
}

__global__ __launch_bounds__(256) void bucket_scan(
        const int* __restrict__ bcnt, int* __restrict__ boff, int* __restrict__ bcur,
        int* __restrict__ row_start, int n, int e, int nb) {
    __shared__ int sh[256];
    int t = threadIdx.x;
    int c = (t < nb) ? bcnt[t] : 0;
    sh[t] = c;
    __syncthreads();
    for (int off = 1; off < 256; off <<= 1) {
        int vp = (t >= off) ? sh[t - off] : 0;
        __syncthreads();
        sh[t] += vp;
        __syncthreads();
    }
    int excl = sh[t] - c;
    if (t < nb) { boff[t] = excl; bcur[t] = excl; }
    if (t == 255) boff[nb] = sh[255];   // == e
    if (t == 0) row_start[n] = e;
}

__global__ __launch_bounds__(256) void bucket_scatter(
        const int* __restrict__ src, const int* __restrict__ dst,
        int* __restrict__ bcur, unsigned* __restrict__ eb, int e) {
    __shared__ int cB[256], gb[256], cur[256];
    int t = threadIdx.x;
    cB[t] = 0;
    __syncthreads();
    int base = blockIdx.x * CB;
    int ps[EPT], pd[EPT];
    #pragma unroll
    for (int k = 0; k < EPT; ++k) {
        int i = base + t + k * 256;
        if (i < e) {
            ps[k] = src[i];
            pd[k] = dst[i];
            atomicAdd(&cB[pd[k] >> BSHIFT], 1);
        } else {
            pd[k] = -1;
        }
    }
    __syncthreads();
    if (cB[t]) gb[t] = atomicAdd(&bcur[t], cB[t]);
    cur[t] = 0;
    __syncthreads();
    #pragma unroll
    for (int k = 0; k < EPT; ++k) {
        if (pd[k] >= 0) {
            int b = pd[k] >> BSHIFT;
            int p = atomicAdd(&cur[b], 1);
            eb[gb[b] + p] = (unsigned)(ps[k] & 0xFFFF) | ((unsigned)(pd[k] & (BNODES - 1)) << 16);
        }
    }
}

__global__ __launch_bounds__(BNODES) void node_hist_scan(
        const unsigned* __restrict__ eb, const int* __restrict__ boff,
        int* __restrict__ rs_local, float* __restrict__ dinv, int n) {
    __shared__ int sh[BNODES];
    int b = blockIdx.x, t = threadIdx.x;
    int s = boff[b], e2 = boff[b + 1];
    sh[t] = 0;
    __syncthreads();
    for (int i = s + t; i < e2; i += BNODES) atomicAdd(&sh[eb[i] >> 16], 1);
    __syncthreads();
    int c = sh[t];
    __syncthreads();
    for (int off = 1; off < BNODES; off <<= 1) {
        int vp = (t >= off) ? sh[t - off] : 0;
        __syncthreads();
        sh[t] += vp;
        __syncthreads();
    }
    int node = b * BNODES + t;
    if (node < n) {
        rs_local[node] = sh[t] - c;
        dinv[node] = 1.0f / sqrtf((float)(c + 1));
    }
}

__global__ __launch_bounds__(BNODES) void final_scatter(
        const unsigned* __restrict__ eb, const int* __restrict__ boff,
        const int* __restrict__ rs_local, int* __restrict__ row_start,
        int* __restrict__ csr_src, int n) {
    __shared__ int cur[BNODES];
    int b = blockIdx.x, t = threadIdx.x;
    int s = boff[b], e2 = boff[b + 1];
    int node = b * BNODES + t;
    int a = 0;
    if (node < n) {
        a = rs_local[node] + s;
        row_start[node] = a;
    }
    cur[t] = a;
    __syncthreads();
    for (int i = s + t; i < e2; i += BNODES) {
        unsigned v = eb[i];
        int p = atomicAdd(&cur[v >> 16], 1);
        csr_src[p] = (int)(v & 0xFFFFu);
    }
}

// ---- W transpose (once, all layers): Wt[l][c][k] = W[l][k][c] ------------

__global__ __launch_bounds__(256) void wtrans_kernel(
        const float* __restrict__ W, float* __restrict__ Wt) {
    int l = blockIdx.x;
    const float* w = W + (size_t)l * D * D;
    float* wt = Wt + (size_t)l * D * D;
    for (int idx = threadIdx.x; idx < D * D; idx += 256) {
        int k = idx >> 6, c = idx & 63;
        wt[c * D + k] = w[idx];
    }
}

// ---- per-layer: H' = dinv .* (X @ W), 4x4 register tile, swizzled LDS ----
// k accumulation order sequential 0..63; the dinv[r] multiply is the SAME f32
// multiply agg used to do per-edge (hoisted to the producer) -> bitwise identical.

__global__ __launch_bounds__(256, 3) void matmul_kernel(
        const float* __restrict__ X, const float* __restrict__ Wt,
        const float* __restrict__ dinv, float* __restrict__ H, int n) {
    __shared__ float4 Xs[64 * 16];   // 16 KB, swizzled
    __shared__ float4 Ws[64 * 16];   // 16 KB, swizzled (Wt rows = W cols)
    int t = threadIdx.x;
    int rowBase = blockIdx.x * 64;
    const float4* X4 = (const float4*)X;
    const float4* Wt4 = (const float4*)Wt;
    #pragma unroll
    for (int p = 0; p < 4; ++p) {
        int rl = (t >> 4) + 16 * p;
        int c4 = t & 15;
        int r = rowBase + rl;
        float4 v = make_float4(0.f, 0.f, 0.f, 0.f);
        if (r < n) v = X4[(size_t)r * 16 + c4];
        Xs[rl * 16 + SW(rl, c4)] = v;
        Ws[rl * 16 + SW(rl, c4)] = Wt4[rl * 16 + c4];
    }
    __syncthreads();
    int wv = t >> 6, lane = t & 63;
    int rg = lane >> 2, cg = lane & 3;
    int r0 = rg * 4;
    int c0 = wv * 16 + cg * 4;
    float acc[4][4] = {};
    #pragma unroll 2
    for (int k4 = 0; k4 < 16; ++k4) {
        float4 xv[4], wvv[4];
        #pragma unroll
        for (int i = 0; i < 4; ++i) xv[i] = Xs[(r0 + i) * 16 + SW(r0 + i, k4)];
        #pragma unroll
        for (int j = 0; j < 4; ++j) wvv[j] = Ws[(c0 + j) * 16 + SW(c0 + j, k4)];
        #pragma unroll
        for (int i = 0; i < 4; ++i)
            #pragma unroll
            for (int j = 0; j < 4; ++j) {
                acc[i][j] += xv[i].x * wvv[j].x;
                acc[i][j] += xv[i].y * wvv[j].y;
                acc[i][j] += xv[i].z * wvv[j].z;
                acc[i][j] += xv[i].w * wvv[j].w;
            }
    }
    #pragma unroll
    for (int i = 0; i < 4; ++i) {
        int r = rowBase + r0 + i;
        if (r < n) {
            float dr = dinv[r];
            float4 o = make_float4(dr * acc[i][0], dr * acc[i][1],
                                   dr * acc[i][2], dr * acc[i][3]);
            *(float4*)&H[(size_t)r * D + c0] = o;
        }
    }
}

// ---- per-layer: aggregate + bias + ReLU (wave per node, lane per feat) --
// H is pre-scaled by dinv; same add order as R5 -> bitwise identical.

__global__ __launch_bounds__(256) void agg_kernel(
        const float* __restrict__ H, const int* __restrict__ csr_src,
        const int* __restrict__ row_start, const float* __restrict__ dinv,
        const float* __restrict__ bias, float* __restrict__ out, int n) {
    int wave = threadIdx.x >> 6, lane = threadIdx.x & 63;
    int v = blockIdx.x * 4 + wave;
    if (v >= n) return;
    float dv = dinv[v];
    float acc = H[(size_t)v * D + lane];          // == dv * (XW)[v]
    int s = row_start[v];
    int e = row_start[v + 1];
    int i = s;
    #pragma unroll 1
    for (; i + 8 <= e; i += 8) {
        int u0 = csr_src[i + 0], u1 = csr_src[i + 1];
        int u2 = csr_src[i + 2], u3 = csr_src[i + 3];
        int u4 = csr_src[i + 4], u5 = csr_src[i + 5];
        int u6 = csr_src[i + 6], u7 = csr_src[i + 7];
        float h0 = H[(size_t)u0 * D + lane];
        float h1 = H[(size_t)u1 * D + lane];
        float h2 = H[(size_t)u2 * D + lane];
        float h3 = H[(size_t)u3 * D + lane];
        float h4 = H[(size_t)u4 * D + lane];
        float h5 = H[(size_t)u5 * D + lane];
        float h6 = H[(size_t)u6 * D + lane];
        float h7 = H[(size_t)u7 * D + lane];
        acc += h0;
        acc += h1;
        acc += h2;
        acc += h3;
        acc += h4;
        acc += h5;
        acc += h6;
        acc += h7;
    }
    for (; i < e; ++i) {
        int u = csr_src[i];
        acc += H[(size_t)u * D + lane];
    }
    out[(size_t)v * D + lane] = fmaxf(dv * acc + bias[lane], 0.f);
}

// ---- mean pool: batch sorted -> binary-search group bounds ---------------

__device__ __forceinline__ int lower_bound_g(const int* __restrict__ b, int n, int g) {
    int lo = 0, hi = n;
    while (lo < hi) { int m = (lo + hi) >> 1; if (b[m] < g) lo = m + 1; else hi = m; }
    return lo;
}

__global__ __launch_bounds__(256) void pool_kernel(
        const float* __restrict__ X, const int* __restrict__ batch,
        float* __restrict__ sums, int n) {
    __shared__ float sh[4][64];
    int g = blockIdx.x >> 2, part = blockIdx.x & 3;
    int gs = lower_bound_g(batch, n, g);
    int ge = lower_bound_g(batch, n, g + 1);
    int wv = threadIdx.x >> 6, lane = threadIdx.x & 63;
    int widx = part * 4 + wv;   // 0..15 waves across the graph
    float acc = 0.f;
    for (int r = gs + widx; r < ge; r += 16)
        acc += X[(size_t)r * D + lane];
    sh[wv][lane] = acc;
    __syncthreads();
    if (wv == 0) {
        float tot = (sh[0][lane] + sh[1][lane]) + (sh[2][lane] + sh[3][lane]);
        atomicAdd(&sums[g * D + lane], tot);
    }
}

__global__ void final_kernel(const float* __restrict__ sums, const int* __restrict__ batch,
                             const float* __restrict__ linW, const float* __restrict__ linb,
                             float* __restrict__ out, int n) {
    int g = blockIdx.x;
    int lane = threadIdx.x;  // blockDim = 64
    int gs = lower_bound_g(batch, n, g);
    int ge = lower_bound_g(batch, n, g + 1);
    float cnt = fmaxf((float)(ge - gs), 1.f);
    float p = (sums[g * D + lane] / cnt) * linW[lane];
    #pragma unroll
    for (int off = 32; off > 0; off >>= 1) p += __shfl_down(p, off, 64);
    if (lane == 0) out[g] = p + linb[0];
}

// ---- orchestration -------------------------------------------------------

extern "C" void kernel_launch(void* const* d_in, const int* in_sizes, int n_in,
                              void* d_out, int out_size, void* d_ws, size_t ws_size,
                              hipStream_t stream) {
    const float* x      = (const float*)d_in[0];  // [N,64]
    const float* conv_W = (const float*)d_in[1];  // [4,64,64]
    const float* conv_b = (const float*)d_in[2];  // [4,64]
    const float* lin_W  = (const float*)d_in[3];  // [64,1]
    const float* lin_b  = (const float*)d_in[4];  // [1]
    const int*   edge   = (const int*)d_in[5];    // [2,E]
    const int*   batch  = (const int*)d_in[6];    // [N]

    const int n = in_sizes[0] / D;
    const int e = in_sizes[5] / 2;
    const int L = in_sizes[1] / (D * D);
    const int G = out_size;

    const int* esrc = edge;
    const int* edst = edge + e;

    // workspace layout (256B aligned)
    char* ws = (char*)d_ws;
    size_t off = 0;
    auto alloc = [&](size_t bytes) -> void* {
        void* p = ws + off;
        off += (bytes + 255) & ~(size_t)255;
        return p;
    };
    const int nb = (n + BNODES - 1) / BNODES;     // buckets (49)
    int*   bcnt      = (int*)alloc(256 * 4);
    int*   boff      = (int*)alloc(257 * 4);
    int*   bcur      = (int*)alloc(256 * 4);
    int*   rs_local  = (int*)alloc((size_t)n * 4);
    float* dinv      = (float*)alloc((size_t)n * 4);
    int*   row_start = (int*)alloc((size_t)(n + 1) * 4);
    int*   csr_src   = (int*)alloc((size_t)e * 4);
    float* wtbuf     = (float*)alloc((size_t)L * D * D * 4);
    float* hbuf      = (float*)alloc((size_t)n * D * 4);
    float* xbuf      = (float*)alloc((size_t)n * D * 4);
    float* sums      = (float*)alloc((size_t)G * D * 4);
    unsigned* eb     = (unsigned*)hbuf;           // alias: eb dead before matmul L0 writes hbuf
    (void)ws_size;

    const int nsums = G * D;
    zero_kernel<<<(256 + nsums + 255) / 256, 256, 0, stream>>>(bcnt, sums, nsums);

    const int pb = (e + CB - 1) / CB;             // partition blocks (196)
    bucket_hist   <<<pb, 256, 0, stream>>>(edst, bcnt, e);
    bucket_scan   <<<1, 256, 0, stream>>>(bcnt, boff, bcur, row_start, n, e, nb);
    bucket_scatter<<<pb, 256, 0, stream>>>(esrc, edst, bcur, eb, e);
    node_hist_scan<<<nb, BNODES, 0, stream>>>(eb, boff, rs_local, dinv, n);
    final_scatter <<<nb, BNODES, 0, stream>>>(eb, boff, rs_local, row_start, csr_src, n);
    wtrans_kernel <<<L, 256, 0, stream>>>(conv_W, wtbuf);

    // layers
    const float* xin = x;
    for (int l = 0; l < L; ++l) {
        matmul_kernel<<<(n + 63) / 64, 256, 0, stream>>>(xin, wtbuf + (size_t)l * D * D,
                                                         dinv, hbuf, n);
        agg_kernel<<<(n + 3) / 4, 256, 0, stream>>>(hbuf, csr_src, row_start, dinv,
                                                    conv_b + (size_t)l * D, xbuf, n);
        xin = xbuf;
    }

    // pool + final linear
    pool_kernel<<<G * 4, 256, 0, stream>>>(xin, batch, sums, n);
    final_kernel<<<G, 64, 0, stream>>>(sums, batch, lin_W, lin_b, (float*)d_out, n);
}

// Round 7
// 260.853 us; speedup vs baseline: 2.8397x; 1.1130x over previous
//
#include <hip/hip_runtime.h>

// GCN forward: 4 x (X@W -> gather-normalize-scatter -> +b, ReLU) -> mean pool -> linear
// N=50000 nodes, E=800000 edges, D=64, L=4, G=64.
// R7: (1) node_hist_scan+final_scatter merged into build_csr (one dispatch, no rs_local
// round-trip). (2) pool+final merged into pool_final (1 block/graph, no atomics, no
// sums buffer/zeroing). (3) agg edge batch 8->16 (2x gathers in flight; add order still
// ascending -> bitwise identical). (4) wtrans folded into setup kernel.
// NOTE: rocprof top-5 "fillBufferAligned 268MB" dispatches are the harness's d_ws
// poison replayed per counter pass -- outside the timed window; ignore.

#define D 64
#define BSHIFT 10                 // nodes per bucket = 1024
#define BNODES 1024
#define EPT 16                    // edges per thread in partition kernels
#define CB (256 * EPT)            // edges per block = 4096
#define SW(r, c4) ((c4) ^ (((r) >> 2) & 15))

// ---- setup: zero bcnt + transpose W (blocks 0..L-1 = wtrans, block L = zero) ----

__global__ __launch_bounds__(256) void setup_kernel(
        const float* __restrict__ W, float* __restrict__ Wt,
        int* __restrict__ bcnt, int L) {
    int b = blockIdx.x;
    if (b < L) {
        const float* w = W + (size_t)b * D * D;
        float* wt = Wt + (size_t)b * D * D;
        for (int idx = threadIdx.x; idx < D * D; idx += 256) {
            int k = idx >> 6, c = idx & 63;
            wt[c * D + k] = w[idx];
        }
    } else {
        bcnt[threadIdx.x] = 0;
    }
}

// ---- CSR build: bucket partition ----------------------------------------

__global__ __launch_bounds__(256) void bucket_hist(
        const int* __restrict__ dst, int* __restrict__ bcnt, int e) {
    __shared__ int c[256];
    int t = threadIdx.x;
    c[t] = 0;
    __syncthreads();
    int base = blockIdx.x * CB;
    #pragma unroll
    for (int k = 0; k < EPT; ++k) {
        int i = base + t + k * 256;
        if (i < e) atomicAdd(&c[dst[i] >> BSHIFT], 1);
    }
    __syncthreads();
    if (c[t]) atomicAdd(&bcnt[t], c[t]);
}

__global__ __launch_bounds__(256) void bucket_scan(
        const int* __restrict__ bcnt, int* __restrict__ boff, int* __restrict__ bcur,
        int* __restrict__ row_start, int n, int e, int nb) {
    __shared__ int sh[256];
    int t = threadIdx.x;
    int c = (t < nb) ? bcnt[t] : 0;
    sh[t] = c;
    __syncthreads();
    for (int off = 1; off < 256; off <<= 1) {
        int vp = (t >= off) ? sh[t - off] : 0;
        __syncthreads();
        sh[t] += vp;
        __syncthreads();
    }
    int excl = sh[t] - c;
    if (t < nb) { boff[t] = excl; bcur[t] = excl; }
    if (t == 255) boff[nb] = sh[255];   // == e
    if (t == 0) row_start[n] = e;
}

__global__ __launch_bounds__(256) void bucket_scatter(
        const int* __restrict__ src, const int* __restrict__ dst,
        int* __restrict__ bcur, unsigned* __restrict__ eb, int e) {
    __shared__ int cB[256], gb[256], cur[256];
    int t = threadIdx.x;
    cB[t] = 0;
    __syncthreads();
    int base = blockIdx.x * CB;
    int ps[EPT], pd[EPT];
    #pragma unroll
    for (int k = 0; k < EPT; ++k) {
        int i = base + t + k * 256;
        if (i < e) {
            ps[k] = src[i];
            pd[k] = dst[i];
            atomicAdd(&cB[pd[k] >> BSHIFT], 1);
        } else {
            pd[k] = -1;
        }
    }
    __syncthreads();
    if (cB[t]) gb[t] = atomicAdd(&bcur[t], cB[t]);
    cur[t] = 0;
    __syncthreads();
    #pragma unroll
    for (int k = 0; k < EPT; ++k) {
        if (pd[k] >= 0) {
            int b = pd[k] >> BSHIFT;
            int p = atomicAdd(&cur[b], 1);
            eb[gb[b] + p] = (unsigned)(ps[k] & 0xFFFF) | ((unsigned)(pd[k] & (BNODES - 1)) << 16);
        }
    }
}

// one block per bucket: node hist (LDS atomics) -> local scan -> absolute row_start,
// dinv, and LDS-cursor scatter, all fused.
__global__ __launch_bounds__(BNODES) void build_csr(
        const unsigned* __restrict__ eb, const int* __restrict__ boff,
        int* __restrict__ row_start, float* __restrict__ dinv,
        int* __restrict__ csr_src, int n) {
    __shared__ int sh[BNODES];
    __shared__ int cur[BNODES];
    int b = blockIdx.x, t = threadIdx.x;
    int s = boff[b], e2 = boff[b + 1];
    sh[t] = 0;
    __syncthreads();
    for (int i = s + t; i < e2; i += BNODES) atomicAdd(&sh[eb[i] >> 16], 1);
    __syncthreads();
    int c = sh[t];
    __syncthreads();
    for (int off = 1; off < BNODES; off <<= 1) {
        int vp = (t >= off) ? sh[t - off] : 0;
        __syncthreads();
        sh[t] += vp;
        __syncthreads();
    }
    int a = sh[t] - c + s;                // absolute row offset
    int node = b * BNODES + t;
    if (node < n) {
        row_start[node] = a;
        dinv[node] = 1.0f / sqrtf((float)(c + 1));
    }
    cur[t] = a;
    __syncthreads();
    for (int i = s + t; i < e2; i += BNODES) {
        unsigned v = eb[i];
        int p = atomicAdd(&cur[v >> 16], 1);
        csr_src[p] = (int)(v & 0xFFFFu);
    }
}

// ---- per-layer: H' = dinv .* (X @ W), 4x4 register tile, swizzled LDS ----

__global__ __launch_bounds__(256, 3) void matmul_kernel(
        const float* __restrict__ X, const float* __restrict__ Wt,
        const float* __restrict__ dinv, float* __restrict__ H, int n) {
    __shared__ float4 Xs[64 * 16];   // 16 KB, swizzled
    __shared__ float4 Ws[64 * 16];   // 16 KB, swizzled (Wt rows = W cols)
    int t = threadIdx.x;
    int rowBase = blockIdx.x * 64;
    const float4* X4 = (const float4*)X;
    const float4* Wt4 = (const float4*)Wt;
    #pragma unroll
    for (int p = 0; p < 4; ++p) {
        int rl = (t >> 4) + 16 * p;
        int c4 = t & 15;
        int r = rowBase + rl;
        float4 v = make_float4(0.f, 0.f, 0.f, 0.f);
        if (r < n) v = X4[(size_t)r * 16 + c4];
        Xs[rl * 16 + SW(rl, c4)] = v;
        Ws[rl * 16 + SW(rl, c4)] = Wt4[rl * 16 + c4];
    }
    __syncthreads();
    int wv = t >> 6, lane = t & 63;
    int rg = lane >> 2, cg = lane & 3;
    int r0 = rg * 4;
    int c0 = wv * 16 + cg * 4;
    float acc[4][4] = {};
    #pragma unroll 2
    for (int k4 = 0; k4 < 16; ++k4) {
        float4 xv[4], wvv[4];
        #pragma unroll
        for (int i = 0; i < 4; ++i) xv[i] = Xs[(r0 + i) * 16 + SW(r0 + i, k4)];
        #pragma unroll
        for (int j = 0; j < 4; ++j) wvv[j] = Ws[(c0 + j) * 16 + SW(c0 + j, k4)];
        #pragma unroll
        for (int i = 0; i < 4; ++i)
            #pragma unroll
            for (int j = 0; j < 4; ++j) {
                acc[i][j] += xv[i].x * wvv[j].x;
                acc[i][j] += xv[i].y * wvv[j].y;
                acc[i][j] += xv[i].z * wvv[j].z;
                acc[i][j] += xv[i].w * wvv[j].w;
            }
    }
    #pragma unroll
    for (int i = 0; i < 4; ++i) {
        int r = rowBase + r0 + i;
        if (r < n) {
            float dr = dinv[r];
            float4 o = make_float4(dr * acc[i][0], dr * acc[i][1],
                                   dr * acc[i][2], dr * acc[i][3]);
            *(float4*)&H[(size_t)r * D + c0] = o;
        }
    }
}

// ---- per-layer: aggregate + bias + ReLU (wave per node, lane per feat) --
// H pre-scaled by dinv; 16 gathers in flight; add order ascending -> bitwise stable.

__global__ __launch_bounds__(256) void agg_kernel(
        const float* __restrict__ H, const int* __restrict__ csr_src,
        const int* __restrict__ row_start, const float* __restrict__ dinv,
        const float* __restrict__ bias, float* __restrict__ out, int n) {
    int wave = threadIdx.x >> 6, lane = threadIdx.x & 63;
    int v = blockIdx.x * 4 + wave;
    if (v >= n) return;
    float dv = dinv[v];
    float acc = H[(size_t)v * D + lane];          // == dv * (XW)[v]
    int s = row_start[v];
    int e = row_start[v + 1];
    int i = s;
    #pragma unroll 1
    for (; i + 16 <= e; i += 16) {
        int u[16];
        float h[16];
        #pragma unroll
        for (int k = 0; k < 16; ++k) u[k] = csr_src[i + k];
        #pragma unroll
        for (int k = 0; k < 16; ++k) h[k] = H[(size_t)u[k] * D + lane];
        #pragma unroll
        for (int k = 0; k < 16; ++k) acc += h[k];
    }
    #pragma unroll 1
    for (; i + 4 <= e; i += 4) {
        int u0 = csr_src[i + 0], u1 = csr_src[i + 1];
        int u2 = csr_src[i + 2], u3 = csr_src[i + 3];
        float h0 = H[(size_t)u0 * D + lane];
        float h1 = H[(size_t)u1 * D + lane];
        float h2 = H[(size_t)u2 * D + lane];
        float h3 = H[(size_t)u3 * D + lane];
        acc += h0;
        acc += h1;
        acc += h2;
        acc += h3;
    }
    for (; i < e; ++i) {
        int u = csr_src[i];
        acc += H[(size_t)u * D + lane];
    }
    out[(size_t)v * D + lane] = fmaxf(dv * acc + bias[lane], 0.f);
}

// ---- mean pool + final linear, one block (1024 thr) per graph ------------

__device__ __forceinline__ int lower_bound_g(const int* __restrict__ b, int n, int g) {
    int lo = 0, hi = n;
    while (lo < hi) { int m = (lo + hi) >> 1; if (b[m] < g) lo = m + 1; else hi = m; }
    return lo;
}

__global__ __launch_bounds__(1024) void pool_final(
        const float* __restrict__ X, const int* __restrict__ batch,
        const float* __restrict__ linW, const float* __restrict__ linb,
        float* __restrict__ out, int n) {
    __shared__ float sh[16][64];
    int g = blockIdx.x;
    int gs = lower_bound_g(batch, n, g);
    int ge = lower_bound_g(batch, n, g + 1);
    int wv = threadIdx.x >> 6, lane = threadIdx.x & 63;
    float acc = 0.f;
    for (int r = gs + wv; r < ge; r += 16)
        acc += X[(size_t)r * D + lane];
    sh[wv][lane] = acc;
    __syncthreads();
    if (wv == 0) {
        float tot = 0.f;
        #pragma unroll
        for (int i = 0; i < 16; ++i) tot += sh[i][lane];
        float cnt = fmaxf((float)(ge - gs), 1.f);
        float p = (tot / cnt) * linW[lane];
        #pragma unroll
        for (int off = 32; off > 0; off >>= 1) p += __shfl_down(p, off, 64);
        if (lane == 0) out[g] = p + linb[0];
    }
}

// ---- orchestration -------------------------------------------------------

extern "C" void kernel_launch(void* const* d_in, const int* in_sizes, int n_in,
                              void* d_out, int out_size, void* d_ws, size_t ws_size,
                              hipStream_t stream) {
    const float* x      = (const float*)d_in[0];  // [N,64]
    const float* conv_W = (const float*)d_in[1];  // [4,64,64]
    const float* conv_b = (const float*)d_in[2];  // [4,64]
    const float* lin_W  = (const float*)d_in[3];  // [64,1]
    const float* lin_b  = (const float*)d_in[4];  // [1]
    const int*   edge   = (const int*)d_in[5];    // [2,E]
    const int*   batch  = (const int*)d_in[6];    // [N]

    const int n = in_sizes[0] / D;
    const int e = in_sizes[5] / 2;
    const int L = in_sizes[1] / (D * D);
    const int G = out_size;

    const int* esrc = edge;
    const int* edst = edge + e;

    // workspace layout (256B aligned)
    char* ws = (char*)d_ws;
    size_t off = 0;
    auto alloc = [&](size_t bytes) -> void* {
        void* p = ws + off;
        off += (bytes + 255) & ~(size_t)255;
        return p;
    };
    const int nb = (n + BNODES - 1) / BNODES;     // buckets (49)
    int*   bcnt      = (int*)alloc(256 * 4);
    int*   boff      = (int*)alloc(257 * 4);
    int*   bcur      = (int*)alloc(256 * 4);
    float* dinv      = (float*)alloc((size_t)n * 4);
    int*   row_start = (int*)alloc((size_t)(n + 1) * 4);
    int*   csr_src   = (int*)alloc((size_t)e * 4);
    float* wtbuf     = (float*)alloc((size_t)L * D * D * 4);
    float* hbuf      = (float*)alloc((size_t)n * D * 4);
    float* xbuf      = (float*)alloc((size_t)n * D * 4);
    unsigned* eb     = (unsigned*)hbuf;           // alias: eb dead before matmul L0 writes hbuf
    (void)ws_size;

    setup_kernel<<<L + 1, 256, 0, stream>>>(conv_W, wtbuf, bcnt, L);

    const int pb = (e + CB - 1) / CB;             // partition blocks (196)
    bucket_hist   <<<pb, 256, 0, stream>>>(edst, bcnt, e);
    bucket_scan   <<<1, 256, 0, stream>>>(bcnt, boff, bcur, row_start, n, e, nb);
    bucket_scatter<<<pb, 256, 0, stream>>>(esrc, edst, bcur, eb, e);
    build_csr     <<<nb, BNODES, 0, stream>>>(eb, boff, row_start, dinv, csr_src, n);

    // layers
    const float* xin = x;
    for (int l = 0; l < L; ++l) {
        matmul_kernel<<<(n + 63) / 64, 256, 0, stream>>>(xin, wtbuf + (size_t)l * D * D,
                                                         dinv, hbuf, n);
        agg_kernel<<<(n + 3) / 4, 256, 0, stream>>>(hbuf, csr_src, row_start, dinv,
                                                    conv_b + (size_t)l * D, xbuf, n);
        xin = xbuf;
    }

    // pool + final linear (single kernel)
    pool_final<<<G, 1024, 0, stream>>>(xin, batch, lin_W, lin_b, (float*)d_out, n);
}

// Round 8
// 251.131 us; speedup vs baseline: 2.9497x; 1.0387x over previous
//
#include <hip/hip_runtime.h>

// GCN forward: 4 x (X@W -> gather-normalize-scatter -> +b, ReLU) -> mean pool -> linear
// N=50000 nodes, E=800000 edges, D=64, L=4, G=64.
// R8: layers 0..2 use agg_fused: after computing the relu'd output row, the wave
// immediately applies the NEXT layer's W via LDS-broadcast dot (k ascending 0..63 ==
// the standalone matmul's order -> bitwise identical) and writes H'(l+1) directly.
// Kills 3 matmul dispatches + 77MB of xbuf round-trip traffic; transform VALU hides
// under agg's gather latency (agg VALUBusy ~4%). Only layer-0 matmul remains.
// NOTE: rocprof top-5 "fillBufferAligned 268MB" dispatches are the harness's d_ws
// poison replayed per counter pass -- outside the timed window; ignore.

#define D 64
#define BSHIFT 10                 // nodes per bucket = 1024
#define BNODES 1024
#define EPT 16                    // edges per thread in partition kernels
#define CB (256 * EPT)            // edges per block = 4096
#define SW(r, c4) ((c4) ^ (((r) >> 2) & 15))

// ---- setup: zero bcnt + transpose W0 (block 0 = wtrans L0, block 1 = zero) ----

__global__ __launch_bounds__(256) void setup_kernel(
        const float* __restrict__ W, float* __restrict__ Wt,
        int* __restrict__ bcnt) {
    int b = blockIdx.x;
    if (b == 0) {
        for (int idx = threadIdx.x; idx < D * D; idx += 256) {
            int k = idx >> 6, c = idx & 63;
            Wt[c * D + k] = W[idx];
        }
    } else {
        bcnt[threadIdx.x] = 0;
    }
}

// ---- CSR build: bucket partition ----------------------------------------

__global__ __launch_bounds__(256) void bucket_hist(
        const int* __restrict__ dst, int* __restrict__ bcnt, int e) {
    __shared__ int c[256];
    int t = threadIdx.x;
    c[t] = 0;
    __syncthreads();
    int base = blockIdx.x * CB;
    #pragma unroll
    for (int k = 0; k < EPT; ++k) {
        int i = base + t + k * 256;
        if (i < e) atomicAdd(&c[dst[i] >> BSHIFT], 1);
    }
    __syncthreads();
    if (c[t]) atomicAdd(&bcnt[t], c[t]);
}

__global__ __launch_bounds__(256) void bucket_scan(
        const int* __restrict__ bcnt, int* __restrict__ boff, int* __restrict__ bcur,
        int* __restrict__ row_start, int n, int e, int nb) {
    __shared__ int sh[256];
    int t = threadIdx.x;
    int c = (t < nb) ? bcnt[t] : 0;
    sh[t] = c;
    __syncthreads();
    for (int off = 1; off < 256; off <<= 1) {
        int vp = (t >= off) ? sh[t - off] : 0;
        __syncthreads();
        sh[t] += vp;
        __syncthreads();
    }
    int excl = sh[t] - c;
    if (t < nb) { boff[t] = excl; bcur[t] = excl; }
    if (t == 255) boff[nb] = sh[255];   // == e
    if (t == 0) row_start[n] = e;
}

__global__ __launch_bounds__(256) void bucket_scatter(
        const int* __restrict__ src, const int* __restrict__ dst,
        int* __restrict__ bcur, unsigned* __restrict__ eb, int e) {
    __shared__ int cB[256], gb[256], cur[256];
    int t = threadIdx.x;
    cB[t] = 0;
    __syncthreads();
    int base = blockIdx.x * CB;
    int ps[EPT], pd[EPT];
    #pragma unroll
    for (int k = 0; k < EPT; ++k) {
        int i = base + t + k * 256;
        if (i < e) {
            ps[k] = src[i];
            pd[k] = dst[i];
            atomicAdd(&cB[pd[k] >> BSHIFT], 1);
        } else {
            pd[k] = -1;
        }
    }
    __syncthreads();
    if (cB[t]) gb[t] = atomicAdd(&bcur[t], cB[t]);
    cur[t] = 0;
    __syncthreads();
    #pragma unroll
    for (int k = 0; k < EPT; ++k) {
        if (pd[k] >= 0) {
            int b = pd[k] >> BSHIFT;
            int p = atomicAdd(&cur[b], 1);
            eb[gb[b] + p] = (unsigned)(ps[k] & 0xFFFF) | ((unsigned)(pd[k] & (BNODES - 1)) << 16);
        }
    }
}

__global__ __launch_bounds__(BNODES) void build_csr(
        const unsigned* __restrict__ eb, const int* __restrict__ boff,
        int* __restrict__ row_start, float* __restrict__ dinv,
        int* __restrict__ csr_src, int n) {
    __shared__ int sh[BNODES];
    __shared__ int cur[BNODES];
    int b = blockIdx.x, t = threadIdx.x;
    int s = boff[b], e2 = boff[b + 1];
    sh[t] = 0;
    __syncthreads();
    for (int i = s + t; i < e2; i += BNODES) atomicAdd(&sh[eb[i] >> 16], 1);
    __syncthreads();
    int c = sh[t];
    __syncthreads();
    for (int off = 1; off < BNODES; off <<= 1) {
        int vp = (t >= off) ? sh[t - off] : 0;
        __syncthreads();
        sh[t] += vp;
        __syncthreads();
    }
    int a = sh[t] - c + s;                // absolute row offset
    int node = b * BNODES + t;
    if (node < n) {
        row_start[node] = a;
        dinv[node] = 1.0f / sqrtf((float)(c + 1));
    }
    cur[t] = a;
    __syncthreads();
    for (int i = s + t; i < e2; i += BNODES) {
        unsigned v = eb[i];
        int p = atomicAdd(&cur[v >> 16], 1);
        csr_src[p] = (int)(v & 0xFFFFu);
    }
}

// ---- layer 0 only: H' = dinv .* (X @ W0), 4x4 register tile --------------

__global__ __launch_bounds__(256, 3) void matmul_kernel(
        const float* __restrict__ X, const float* __restrict__ Wt,
        const float* __restrict__ dinv, float* __restrict__ H, int n) {
    __shared__ float4 Xs[64 * 16];   // 16 KB, swizzled
    __shared__ float4 Ws[64 * 16];   // 16 KB, swizzled (Wt rows = W cols)
    int t = threadIdx.x;
    int rowBase = blockIdx.x * 64;
    const float4* X4 = (const float4*)X;
    const float4* Wt4 = (const float4*)Wt;
    #pragma unroll
    for (int p = 0; p < 4; ++p) {
        int rl = (t >> 4) + 16 * p;
        int c4 = t & 15;
        int r = rowBase + rl;
        float4 v = make_float4(0.f, 0.f, 0.f, 0.f);
        if (r < n) v = X4[(size_t)r * 16 + c4];
        Xs[rl * 16 + SW(rl, c4)] = v;
        Ws[rl * 16 + SW(rl, c4)] = Wt4[rl * 16 + c4];
    }
    __syncthreads();
    int wv = t >> 6, lane = t & 63;
    int rg = lane >> 2, cg = lane & 3;
    int r0 = rg * 4;
    int c0 = wv * 16 + cg * 4;
    float acc[4][4] = {};
    #pragma unroll 2
    for (int k4 = 0; k4 < 16; ++k4) {
        float4 xv[4], wvv[4];
        #pragma unroll
        for (int i = 0; i < 4; ++i) xv[i] = Xs[(r0 + i) * 16 + SW(r0 + i, k4)];
        #pragma unroll
        for (int j = 0; j < 4; ++j) wvv[j] = Ws[(c0 + j) * 16 + SW(c0 + j, k4)];
        #pragma unroll
        for (int i = 0; i < 4; ++i)
            #pragma unroll
            for (int j = 0; j < 4; ++j) {
                acc[i][j] += xv[i].x * wvv[j].x;
                acc[i][j] += xv[i].y * wvv[j].y;
                acc[i][j] += xv[i].z * wvv[j].z;
                acc[i][j] += xv[i].w * wvv[j].w;
            }
    }
    #pragma unroll
    for (int i = 0; i < 4; ++i) {
        int r = rowBase + r0 + i;
        if (r < n) {
            float dr = dinv[r];
            float4 o = make_float4(dr * acc[i][0], dr * acc[i][1],
                                   dr * acc[i][2], dr * acc[i][3]);
            *(float4*)&H[(size_t)r * D + c0] = o;
        }
    }
}

// ---- layers 0..2: aggregate + bias + ReLU + NEXT layer's transform -------
// Wave-local row staged in LDS; transform k ascending 0..63 (== matmul order).
// Writes H'(l+1) = dinv[v] * (relu_row @ Wn) directly.

__global__ __launch_bounds__(256) void agg_fused(
        const float* __restrict__ H, const int* __restrict__ csr_src,
        const int* __restrict__ row_start, const float* __restrict__ dinv,
        const float* __restrict__ bias, const float* __restrict__ Wn,
        float* __restrict__ out, int n) {
    __shared__ float Wsh[D * D];        // W(l+1) in [k][c] layout, 16 KB
    __shared__ float rowsh[4][D];
    int t = threadIdx.x;
    {
        const float4* W4 = (const float4*)Wn;
        float4* Ws4 = (float4*)Wsh;
        #pragma unroll
        for (int i = t; i < D * D / 4; i += 256) Ws4[i] = W4[i];
    }
    __syncthreads();                     // all threads reach (no early return)
    int wave = t >> 6, lane = t & 63;
    int v = blockIdx.x * 4 + wave;
    bool active = v < n;
    float dv = 0.f, o = 0.f;
    if (active) {
        dv = dinv[v];
        float acc = H[(size_t)v * D + lane];      // == dv * (XW)[v]
        int s = row_start[v];
        int e = row_start[v + 1];
        int i = s;
        #pragma unroll 1
        for (; i + 16 <= e; i += 16) {
            int u[16];
            float h[16];
            #pragma unroll
            for (int k = 0; k < 16; ++k) u[k] = csr_src[i + k];
            #pragma unroll
            for (int k = 0; k < 16; ++k) h[k] = H[(size_t)u[k] * D + lane];
            #pragma unroll
            for (int k = 0; k < 16; ++k) acc += h[k];
        }
        #pragma unroll 1
        for (; i + 4 <= e; i += 4) {
            int u0 = csr_src[i + 0], u1 = csr_src[i + 1];
            int u2 = csr_src[i + 2], u3 = csr_src[i + 3];
            float h0 = H[(size_t)u0 * D + lane];
            float h1 = H[(size_t)u1 * D + lane];
            float h2 = H[(size_t)u2 * D + lane];
            float h3 = H[(size_t)u3 * D + lane];
            acc += h0;
            acc += h1;
            acc += h2;
            acc += h3;
        }
        for (; i < e; ++i) {
            int u = csr_src[i];
            acc += H[(size_t)u * D + lane];
        }
        o = fmaxf(dv * acc + bias[lane], 0.f);
    }
    rowsh[wave][lane] = o;               // wave-local; HW orders ds_write->ds_read
    if (active) {
        float accT = 0.f;
        #pragma unroll 8
        for (int k = 0; k < D; ++k)      // k ascending == standalone matmul's order
            accT += rowsh[wave][k] * Wsh[k * D + lane];
        out[(size_t)v * D + lane] = dv * accT;
    }
}

// ---- layer 3: aggregate + bias + ReLU (no transform) ---------------------

__global__ __launch_bounds__(256) void agg_kernel(
        const float* __restrict__ H, const int* __restrict__ csr_src,
        const int* __restrict__ row_start, const float* __restrict__ dinv,
        const float* __restrict__ bias, float* __restrict__ out, int n) {
    int wave = threadIdx.x >> 6, lane = threadIdx.x & 63;
    int v = blockIdx.x * 4 + wave;
    if (v >= n) return;
    float dv = dinv[v];
    float acc = H[(size_t)v * D + lane];
    int s = row_start[v];
    int e = row_start[v + 1];
    int i = s;
    #pragma unroll 1
    for (; i + 16 <= e; i += 16) {
        int u[16];
        float h[16];
        #pragma unroll
        for (int k = 0; k < 16; ++k) u[k] = csr_src[i + k];
        #pragma unroll
        for (int k = 0; k < 16; ++k) h[k] = H[(size_t)u[k] * D + lane];
        #pragma unroll
        for (int k = 0; k < 16; ++k) acc += h[k];
    }
    #pragma unroll 1
    for (; i + 4 <= e; i += 4) {
        int u0 = csr_src[i + 0], u1 = csr_src[i + 1];
        int u2 = csr_src[i + 2], u3 = csr_src[i + 3];
        float h0 = H[(size_t)u0 * D + lane];
        float h1 = H[(size_t)u1 * D + lane];
        float h2 = H[(size_t)u2 * D + lane];
        float h3 = H[(size_t)u3 * D + lane];
        acc += h0;
        acc += h1;
        acc += h2;
        acc += h3;
    }
    for (; i < e; ++i) {
        int u = csr_src[i];
        acc += H[(size_t)u * D + lane];
    }
    out[(size_t)v * D + lane] = fmaxf(dv * acc + bias[lane], 0.f);
}

// ---- mean pool + final linear, one block (1024 thr) per graph ------------

__device__ __forceinline__ int lower_bound_g(const int* __restrict__ b, int n, int g) {
    int lo = 0, hi = n;
    while (lo < hi) { int m = (lo + hi) >> 1; if (b[m] < g) lo = m + 1; else hi = m; }
    return lo;
}

__global__ __launch_bounds__(1024) void pool_final(
        const float* __restrict__ X, const int* __restrict__ batch,
        const float* __restrict__ linW, const float* __restrict__ linb,
        float* __restrict__ out, int n) {
    __shared__ float sh[16][64];
    int g = blockIdx.x;
    int gs = lower_bound_g(batch, n, g);
    int ge = lower_bound_g(batch, n, g + 1);
    int wv = threadIdx.x >> 6, lane = threadIdx.x & 63;
    float acc = 0.f;
    for (int r = gs + wv; r < ge; r += 16)
        acc += X[(size_t)r * D + lane];
    sh[wv][lane] = acc;
    __syncthreads();
    if (wv == 0) {
        float tot = 0.f;
        #pragma unroll
        for (int i = 0; i < 16; ++i) tot += sh[i][lane];
        float cnt = fmaxf((float)(ge - gs), 1.f);
        float p = (tot / cnt) * linW[lane];
        #pragma unroll
        for (int off = 32; off > 0; off >>= 1) p += __shfl_down(p, off, 64);
        if (lane == 0) out[g] = p + linb[0];
    }
}

// ---- orchestration -------------------------------------------------------

extern "C" void kernel_launch(void* const* d_in, const int* in_sizes, int n_in,
                              void* d_out, int out_size, void* d_ws, size_t ws_size,
                              hipStream_t stream) {
    const float* x      = (const float*)d_in[0];  // [N,64]
    const float* conv_W = (const float*)d_in[1];  // [4,64,64]
    const float* conv_b = (const float*)d_in[2];  // [4,64]
    const float* lin_W  = (const float*)d_in[3];  // [64,1]
    const float* lin_b  = (const float*)d_in[4];  // [1]
    const int*   edge   = (const int*)d_in[5];    // [2,E]
    const int*   batch  = (const int*)d_in[6];    // [N]

    const int n = in_sizes[0] / D;
    const int e = in_sizes[5] / 2;
    const int L = in_sizes[1] / (D * D);          // 4
    const int G = out_size;

    const int* esrc = edge;
    const int* edst = edge + e;

    // workspace layout (256B aligned)
    char* ws = (char*)d_ws;
    size_t off = 0;
    auto alloc = [&](size_t bytes) -> void* {
        void* p = ws + off;
        off += (bytes + 255) & ~(size_t)255;
        return p;
    };
    const int nb = (n + BNODES - 1) / BNODES;     // buckets (49)
    int*   bcnt      = (int*)alloc(256 * 4);
    int*   boff      = (int*)alloc(257 * 4);
    int*   bcur      = (int*)alloc(256 * 4);
    float* dinv      = (float*)alloc((size_t)n * 4);
    int*   row_start = (int*)alloc((size_t)(n + 1) * 4);
    int*   csr_src   = (int*)alloc((size_t)e * 4);
    float* wtbuf     = (float*)alloc((size_t)D * D * 4);
    float* hbuf      = (float*)alloc((size_t)n * D * 4);
    float* xbuf      = (float*)alloc((size_t)n * D * 4);
    unsigned* eb     = (unsigned*)hbuf;           // alias: eb dead before matmul writes hbuf
    (void)ws_size;
    (void)L;

    setup_kernel<<<2, 256, 0, stream>>>(conv_W, wtbuf, bcnt);

    const int pb = (e + CB - 1) / CB;             // partition blocks (196)
    bucket_hist   <<<pb, 256, 0, stream>>>(edst, bcnt, e);
    bucket_scan   <<<1, 256, 0, stream>>>(bcnt, boff, bcur, row_start, n, e, nb);
    bucket_scatter<<<pb, 256, 0, stream>>>(esrc, edst, bcur, eb, e);
    build_csr     <<<nb, BNODES, 0, stream>>>(eb, boff, row_start, dinv, csr_src, n);

    const int ablocks = (n + 3) / 4;

    // layer 0 linear transform (external input)
    matmul_kernel<<<(n + 63) / 64, 256, 0, stream>>>(x, wtbuf, dinv, hbuf, n);
    // layers 0..2: agg + fused next-layer transform (ping-pong hbuf/xbuf)
    agg_fused<<<ablocks, 256, 0, stream>>>(hbuf, csr_src, row_start, dinv,
                                           conv_b + 0 * D, conv_W + 1 * D * D, xbuf, n);
    agg_fused<<<ablocks, 256, 0, stream>>>(xbuf, csr_src, row_start, dinv,
                                           conv_b + 1 * D, conv_W + 2 * D * D, hbuf, n);
    agg_fused<<<ablocks, 256, 0, stream>>>(hbuf, csr_src, row_start, dinv,
                                           conv_b + 2 * D, conv_W + 3 * D * D, xbuf, n);
    // layer 3: plain agg
    agg_kernel<<<ablocks, 256, 0, stream>>>(xbuf, csr_src, row_start, dinv,
                                            conv_b + 3 * D, hbuf, n);

    // pool + final linear (single kernel)
    pool_final<<<G, 1024, 0, stream>>>(hbuf, batch, lin_W, lin_b, (float*)d_out, n);
}